// Round 2
// baseline (1011.215 us; speedup 1.0000x reference)
//
#include <hip/hip_runtime.h>
#include <math.h>

#define NN 20000
#define NE 320000
#define NG 128

// ---------------------------------------------------------------------------
// CSR build: count -> exclusive scan -> fill (src ids grouped by dst)
// ---------------------------------------------------------------------------
__global__ void count_kernel(const int* __restrict__ dst, int* __restrict__ cnt, int E) {
    int i = blockIdx.x * blockDim.x + threadIdx.x;
    if (i < E) atomicAdd(&cnt[dst[i]], 1);
}

__global__ __launch_bounds__(1024) void scan_kernel(const int* __restrict__ cnt,
                                                    int* __restrict__ row_start, int n) {
    __shared__ int sh[1024];
    __shared__ int carry;
    int tid = threadIdx.x;
    if (tid == 0) carry = 0;
    __syncthreads();
    for (int base = 0; base < n; base += 1024) {
        int v = (base + tid < n) ? cnt[base + tid] : 0;
        sh[tid] = v;
        __syncthreads();
        for (int off = 1; off < 1024; off <<= 1) {
            int t = (tid >= off) ? sh[tid - off] : 0;
            __syncthreads();
            sh[tid] += t;
            __syncthreads();
        }
        int incl = sh[tid];
        int c0 = carry;
        int tot = sh[1023];
        __syncthreads();
        if (base + tid < n) row_start[base + tid] = c0 + incl - v;
        if (tid == 0) carry = c0 + tot;
        __syncthreads();
    }
    if (tid == 0) row_start[n] = carry;
}

__global__ void fill_kernel(const int* __restrict__ src, const int* __restrict__ dst,
                            const int* __restrict__ row_start, int* __restrict__ cursor,
                            int* __restrict__ csr_src, int E) {
    int i = blockIdx.x * blockDim.x + threadIdx.x;
    if (i < E) {
        int d = dst[i];
        int pos = atomicAdd(&cursor[d], 1);
        csr_src[row_start[d] + pos] = src[i];
    }
}

// ---------------------------------------------------------------------------
// GEMM: C[m,n] = sum_k A[m,k] * B[n,k]   (A: MxK row-major, B: NxK row-major)
// ---------------------------------------------------------------------------
#define BM 64
#define BN 64
#define BK 16
__global__ __launch_bounds__(256) void gemm_nt_kernel(const float* __restrict__ A,
                                                      const float* __restrict__ B,
                                                      float* __restrict__ C,
                                                      int M, int N, int K) {
    __shared__ float As[BM][BK + 1];
    __shared__ float Bs[BN][BK + 1];
    const int tid = threadIdx.x;
    const int bm = blockIdx.y * BM;
    const int bn = blockIdx.x * BN;
    const int tx = tid % 16, ty = tid / 16;
    float acc[4][4] = {};
    for (int k0 = 0; k0 < K; k0 += BK) {
        for (int i = tid; i < BM * BK; i += 256) {
            int r = i / BK, c = i % BK;
            int gm = bm + r, gk = k0 + c;
            As[r][c] = (gm < M) ? A[(size_t)gm * K + gk] : 0.f;
        }
        for (int i = tid; i < BN * BK; i += 256) {
            int r = i / BK, c = i % BK;
            int gn = bn + r, gk = k0 + c;
            Bs[r][c] = (gn < N) ? B[(size_t)gn * K + gk] : 0.f;
        }
        __syncthreads();
        #pragma unroll
        for (int kk = 0; kk < BK; ++kk) {
            float a[4], b[4];
            #pragma unroll
            for (int i = 0; i < 4; ++i) a[i] = As[ty * 4 + i][kk];
            #pragma unroll
            for (int j = 0; j < 4; ++j) b[j] = Bs[tx * 4 + j][kk];
            #pragma unroll
            for (int i = 0; i < 4; ++i)
                #pragma unroll
                for (int j = 0; j < 4; ++j) acc[i][j] += a[i] * b[j];
        }
        __syncthreads();
    }
    for (int i = 0; i < 4; ++i) {
        int gm = bm + ty * 4 + i;
        if (gm >= M) continue;
        for (int j = 0; j < 4; ++j) {
            int gn = bn + tx * 4 + j;
            if (gn < N) C[(size_t)gm * N + gn] = acc[i][j];
        }
    }
}

// ---------------------------------------------------------------------------
// Attention scalars: a_src[n,h] = dot(h[n,h,:], att_src[h,:]), same for dst
// One wave per (n, h).
// ---------------------------------------------------------------------------
template <int H, int C>
__global__ void att_kernel(const float* __restrict__ h, const float* __restrict__ att_src,
                           const float* __restrict__ att_dst, float* __restrict__ a_src,
                           float* __restrict__ a_dst, int N) {
    int wid = (blockIdx.x * blockDim.x + threadIdx.x) >> 6;
    int lane = threadIdx.x & 63;
    if (wid >= N * H) return;
    int n = wid / H, hh = wid % H;
    const float* hp = h + (size_t)n * (H * C) + hh * C;
    float s1 = 0.f, s2 = 0.f;
    for (int c = lane; c < C; c += 64) {
        float v = hp[c];
        s1 += v * att_src[hh * C + c];
        s2 += v * att_dst[hh * C + c];
    }
    for (int off = 32; off; off >>= 1) {
        s1 += __shfl_down(s1, off);
        s2 += __shfl_down(s2, off);
    }
    if (lane == 0) { a_src[wid] = s1; a_dst[wid] = s2; }
}

// ---------------------------------------------------------------------------
// GAT aggregate: per (dst node, head): segment softmax over incoming edges
// (incl. implicit self loop) + weighted sum of h[src], + bias + relu.
// One wave per (n, h), lanes over channels.
// ---------------------------------------------------------------------------
__device__ __forceinline__ float lrelu(float x) { return x >= 0.f ? x : 0.2f * x; }

template <int H, int C>
__global__ void gat_aggregate(const float* __restrict__ h, const float* __restrict__ a_src,
                              const float* __restrict__ a_dst, const int* __restrict__ row_start,
                              const int* __restrict__ csr_src, const float* __restrict__ bias,
                              float* __restrict__ out, int N) {
    int wid = (blockIdx.x * blockDim.x + threadIdx.x) >> 6;
    int lane = threadIdx.x & 63;
    if (wid >= N * H) return;
    int n = wid / H, hh = wid % H;
    float adst = a_dst[n * H + hh];
    int rs = row_start[n], re = row_start[n + 1];

    // pass 1: max (self loop included)
    float e_self = lrelu(a_src[n * H + hh] + adst);
    float m = e_self;
    for (int i = rs; i < re; ++i) {
        int s = csr_src[i];
        m = fmaxf(m, lrelu(a_src[s * H + hh] + adst));
    }

    constexpr int NJ = (C + 63) / 64;
    float acc[NJ];
    #pragma unroll
    for (int j = 0; j < NJ; ++j) acc[j] = 0.f;
    float ssum = 0.f;

    {   // self loop
        float w = __expf(e_self - m);
        ssum += w;
        const float* hp = h + (size_t)n * (H * C) + hh * C;
        #pragma unroll
        for (int j = 0; j < NJ; ++j) {
            int c = j * 64 + lane;
            if (c < C) acc[j] += w * hp[c];
        }
    }
    for (int i = rs; i < re; ++i) {
        int s = csr_src[i];
        float w = __expf(lrelu(a_src[s * H + hh] + adst) - m);
        ssum += w;
        const float* hp = h + (size_t)s * (H * C) + hh * C;
        #pragma unroll
        for (int j = 0; j < NJ; ++j) {
            int c = j * 64 + lane;
            if (c < C) acc[j] += w * hp[c];
        }
    }
    float inv = 1.f / (ssum + 1e-16f);
    float* op = out + (size_t)n * (H * C) + hh * C;
    #pragma unroll
    for (int j = 0; j < NJ; ++j) {
        int c = j * 64 + lane;
        if (c < C) {
            float v = acc[j] * inv + bias[hh * C + c];
            op[c] = v > 0.f ? v : 0.f;
        }
    }
}

// ---------------------------------------------------------------------------
// global_add_pool: one wave per node, lanes 0..31 handle the 32 channels
// ---------------------------------------------------------------------------
__global__ void pool_kernel(const float* __restrict__ x, const int* __restrict__ batch,
                            float* __restrict__ g, int N) {
    int wid = (blockIdx.x * blockDim.x + threadIdx.x) >> 6;
    int lane = threadIdx.x & 63;
    if (wid >= N || lane >= 32) return;
    int b = batch[wid];
    atomicAdd(&g[b * 32 + lane], x[(size_t)wid * 32 + lane]);
}

__global__ void mlp1_kernel(const float* __restrict__ g, const float* __restrict__ w,
                            const float* __restrict__ b, float* __restrict__ hid) {
    int idx = blockIdx.x * blockDim.x + threadIdx.x;
    if (idx >= NG * 1024) return;
    int gr = idx >> 10, o = idx & 1023;
    float s = b[o];
    const float* gp = g + gr * 32;
    const float* wp = w + o * 32;
    #pragma unroll
    for (int k = 0; k < 32; ++k) s += gp[k] * wp[k];
    hid[idx] = s > 0.f ? s : 0.f;
}

__global__ void mlp2_kernel(const float* __restrict__ hid, const float* __restrict__ w2,
                            const float* __restrict__ b2, float* __restrict__ outp) {
    int wid = (blockIdx.x * blockDim.x + threadIdx.x) >> 6;
    int lane = threadIdx.x & 63;
    if (wid >= NG) return;
    float s = 0.f;
    for (int k = lane; k < 1024; k += 64) s += hid[wid * 1024 + k] * w2[k];
    for (int off = 32; off; off >>= 1) s += __shfl_down(s, off);
    if (lane == 0) outp[wid] = 1.f / (1.f + expf(-(s + b2[0])));
}

// ---------------------------------------------------------------------------
static inline size_t al256(size_t x) { return (x + 255) & ~(size_t)255; }

extern "C" void kernel_launch(void* const* d_in, const int* in_sizes, int n_in,
                              void* d_out, int out_size, void* d_ws, size_t ws_size,
                              hipStream_t stream) {
    const float* x      = (const float*)d_in[0];
    const float* W1     = (const float*)d_in[1];
    const float* as1    = (const float*)d_in[2];
    const float* ad1    = (const float*)d_in[3];
    const float* b1     = (const float*)d_in[4];
    const float* W2     = (const float*)d_in[5];
    const float* as2    = (const float*)d_in[6];
    const float* ad2    = (const float*)d_in[7];
    const float* b2     = (const float*)d_in[8];
    const float* W3     = (const float*)d_in[9];
    const float* as3    = (const float*)d_in[10];
    const float* ad3    = (const float*)d_in[11];
    const float* b3     = (const float*)d_in[12];
    const float* lin_w  = (const float*)d_in[13];
    const float* lin_b  = (const float*)d_in[14];
    const float* lin2_w = (const float*)d_in[15];
    const float* lin2_b = (const float*)d_in[16];
    const int*   ei     = (const int*)d_in[17];
    const int*   batch  = (const int*)d_in[18];
    float* outp = (float*)d_out;

    const int E = in_sizes[17] / 2;
    const int* e_src = ei;
    const int* e_dst = ei + E;

    // workspace carve-up
    char* p = (char*)d_ws;
    float* h_buf   = (float*)p; p += al256((size_t)NN * 480 * 4);
    float* o_buf   = (float*)p; p += al256((size_t)NN * 480 * 4);
    float* asrc    = (float*)p; p += al256((size_t)NN * 5 * 4);
    float* adst    = (float*)p; p += al256((size_t)NN * 5 * 4);
    int*   row_st  = (int*)p;   p += al256((size_t)(NN + 1) * 4);
    int*   cnt     = (int*)p;   p += al256((size_t)NN * 4);   // reused as cursor
    int*   csr_src = (int*)p;   p += al256((size_t)NE * 4);
    float* gpool   = (float*)p; p += al256((size_t)NG * 32 * 4);
    float* hidden  = (float*)p; p += al256((size_t)NG * 1024 * 4);
    (void)ws_size; (void)n_in; (void)out_size;

    // ---- CSR build ----
    hipMemsetAsync(cnt, 0, NN * 4, stream);
    count_kernel<<<(E + 255) / 256, 256, 0, stream>>>(e_dst, cnt, E);
    scan_kernel<<<1, 1024, 0, stream>>>(cnt, row_st, NN);
    hipMemsetAsync(cnt, 0, NN * 4, stream);
    fill_kernel<<<(E + 255) / 256, 256, 0, stream>>>(e_src, e_dst, row_st, cnt, csr_src, E);

    dim3 blk(256);
    // ---- layer 1: in 64 -> H=5, C=64 (out width 320) ----
    {
        dim3 g((320 + BN - 1) / BN, (NN + BM - 1) / BM);
        gemm_nt_kernel<<<g, blk, 0, stream>>>(x, W1, h_buf, NN, 320, 64);
        int waves = NN * 5;
        att_kernel<5, 64><<<(waves * 64 + 255) / 256, blk, 0, stream>>>(h_buf, as1, ad1, asrc, adst, NN);
        gat_aggregate<5, 64><<<(waves * 64 + 255) / 256, blk, 0, stream>>>(h_buf, asrc, adst, row_st, csr_src, b1, o_buf, NN);
    }
    // ---- layer 2: in 320 -> H=5, C=96 (out width 480) ----
    {
        dim3 g((480 + BN - 1) / BN, (NN + BM - 1) / BM);
        gemm_nt_kernel<<<g, blk, 0, stream>>>(o_buf, W2, h_buf, NN, 480, 320);
        int waves = NN * 5;
        att_kernel<5, 96><<<(waves * 64 + 255) / 256, blk, 0, stream>>>(h_buf, as2, ad2, asrc, adst, NN);
        gat_aggregate<5, 96><<<(waves * 64 + 255) / 256, blk, 0, stream>>>(h_buf, asrc, adst, row_st, csr_src, b2, o_buf, NN);
    }
    // ---- layer 3: in 480 -> H=1, C=32 (out width 32) ----
    {
        dim3 g((32 + BN - 1) / BN, (NN + BM - 1) / BM);
        gemm_nt_kernel<<<g, blk, 0, stream>>>(o_buf, W3, h_buf, NN, 32, 480);
        int waves = NN;
        att_kernel<1, 32><<<(waves * 64 + 255) / 256, blk, 0, stream>>>(h_buf, as3, ad3, asrc, adst, NN);
        gat_aggregate<1, 32><<<(waves * 64 + 255) / 256, blk, 0, stream>>>(h_buf, asrc, adst, row_st, csr_src, b3, o_buf, NN);
    }
    // ---- pool + MLP ----
    hipMemsetAsync(gpool, 0, NG * 32 * 4, stream);
    pool_kernel<<<(NN * 64 + 255) / 256, blk, 0, stream>>>(o_buf, batch, gpool, NN);
    mlp1_kernel<<<(NG * 1024 + 255) / 256, blk, 0, stream>>>(gpool, lin_w, lin_b, hidden);
    mlp2_kernel<<<(NG * 64 + 255) / 256, blk, 0, stream>>>(hidden, lin2_w, lin2_b, outp);
}

// Round 3
// 514.117 us; speedup vs baseline: 1.9669x; 1.9669x over previous
//
#include <hip/hip_runtime.h>
#include <math.h>

#define NN 20000
#define NE 320000
#define NG 128

typedef short short8 __attribute__((ext_vector_type(8)));
typedef float f32x4 __attribute__((ext_vector_type(4)));
typedef unsigned short ushort;

__device__ __forceinline__ float b2f(ushort u) {
    unsigned int v = ((unsigned int)u) << 16;
    return __uint_as_float(v);
}
__device__ __forceinline__ ushort f2b(float f) {
    unsigned int u = __float_as_uint(f);
    u = (u + 0x7fff + ((u >> 16) & 1)) >> 16;   // RNE
    return (ushort)u;
}
__device__ __forceinline__ float lrelu(float x) { return x >= 0.f ? x : 0.2f * x; }

// ---------------------------------------------------------------------------
// f32 -> bf16 convert
// ---------------------------------------------------------------------------
__global__ void f2b_kernel(const float* __restrict__ in, ushort* __restrict__ out, int n) {
    int i = blockIdx.x * blockDim.x + threadIdx.x;
    if (i < n) out[i] = f2b(in[i]);
}

// ---------------------------------------------------------------------------
// CSR build: count -> exclusive scan -> fill
// ---------------------------------------------------------------------------
__global__ void count_kernel(const int* __restrict__ dst, int* __restrict__ cnt, int E) {
    int i = blockIdx.x * blockDim.x + threadIdx.x;
    if (i < E) atomicAdd(&cnt[dst[i]], 1);
}

__global__ __launch_bounds__(1024) void scan_kernel(const int* __restrict__ cnt,
                                                    int* __restrict__ row_start, int n) {
    __shared__ int sh[1024];
    __shared__ int carry;
    int tid = threadIdx.x;
    if (tid == 0) carry = 0;
    __syncthreads();
    for (int base = 0; base < n; base += 1024) {
        int v = (base + tid < n) ? cnt[base + tid] : 0;
        sh[tid] = v;
        __syncthreads();
        for (int off = 1; off < 1024; off <<= 1) {
            int t = (tid >= off) ? sh[tid - off] : 0;
            __syncthreads();
            sh[tid] += t;
            __syncthreads();
        }
        int incl = sh[tid];
        int c0 = carry;
        int tot = sh[1023];
        __syncthreads();
        if (base + tid < n) row_start[base + tid] = c0 + incl - v;
        if (tid == 0) carry = c0 + tot;
        __syncthreads();
    }
    if (tid == 0) row_start[n] = carry;
}

__global__ void fill_kernel(const int* __restrict__ src, const int* __restrict__ dst,
                            const int* __restrict__ row_start, int* __restrict__ cursor,
                            int* __restrict__ csr_src, int E) {
    int i = blockIdx.x * blockDim.x + threadIdx.x;
    if (i < E) {
        int d = dst[i];
        int pos = atomicAdd(&cursor[d], 1);
        csr_src[row_start[d] + pos] = src[i];
    }
}

// ---------------------------------------------------------------------------
// MFMA GEMM: C[m,n] = sum_k A[m,k]*B[n,k], A/B bf16 row-major, C bf16.
// Block = 256 threads = 4 waves. BM=64 (16 rows/wave), BN=32 (2 col frags).
// K multiple of 32, N multiple of 32. Direct-from-global fragments (no LDS).
// ---------------------------------------------------------------------------
__global__ __launch_bounds__(256) void gemm_mfma_kernel(const ushort* __restrict__ A,
                                                        const ushort* __restrict__ B,
                                                        ushort* __restrict__ C,
                                                        int M, int N, int K) {
    const int tid = threadIdx.x;
    const int w = tid >> 6;
    const int lane = tid & 63;
    const int l15 = lane & 15;
    const int lhi = lane >> 4;           // 0..3
    const int bm = blockIdx.y * 64;
    const int bn = blockIdx.x * 32;

    int arow = bm + w * 16 + l15;
    if (arow >= M) arow = M - 1;         // clamp; stores are masked
    const ushort* ap = A + (size_t)arow * K + lhi * 8;
    const ushort* bp0 = B + (size_t)(bn + l15) * K + lhi * 8;
    const ushort* bp1 = B + (size_t)(bn + 16 + l15) * K + lhi * 8;

    f32x4 acc0 = {0.f, 0.f, 0.f, 0.f};
    f32x4 acc1 = {0.f, 0.f, 0.f, 0.f};
    for (int k0 = 0; k0 < K; k0 += 32) {
        short8 a  = *(const short8*)(ap + k0);
        short8 b0 = *(const short8*)(bp0 + k0);
        short8 b1 = *(const short8*)(bp1 + k0);
        acc0 = __builtin_amdgcn_mfma_f32_16x16x32_bf16(a, b0, acc0, 0, 0, 0);
        acc1 = __builtin_amdgcn_mfma_f32_16x16x32_bf16(a, b1, acc1, 0, 0, 0);
    }
    #pragma unroll
    for (int j = 0; j < 4; ++j) {
        int row = bm + w * 16 + lhi * 4 + j;
        if (row < M) {
            C[(size_t)row * N + bn + l15]      = f2b(acc0[j]);
            C[(size_t)row * N + bn + 16 + l15] = f2b(acc1[j]);
        }
    }
}

// ---------------------------------------------------------------------------
// Attention scalars from bf16 h. One wave per (n, h).
// ---------------------------------------------------------------------------
template <int H, int C>
__global__ void att_kernel(const ushort* __restrict__ h, const float* __restrict__ att_src,
                           const float* __restrict__ att_dst, float* __restrict__ a_src,
                           float* __restrict__ a_dst, int N) {
    int wid = (blockIdx.x * blockDim.x + threadIdx.x) >> 6;
    int lane = threadIdx.x & 63;
    if (wid >= N * H) return;
    int n = wid / H, hh = wid % H;
    const ushort* hp = h + (size_t)n * (H * C) + hh * C;
    float s1 = 0.f, s2 = 0.f;
    for (int c = lane; c < C; c += 64) {
        float v = b2f(hp[c]);
        s1 += v * att_src[hh * C + c];
        s2 += v * att_dst[hh * C + c];
    }
    for (int off = 32; off; off >>= 1) {
        s1 += __shfl_down(s1, off);
        s2 += __shfl_down(s2, off);
    }
    if (lane == 0) { a_src[wid] = s1; a_dst[wid] = s2; }
}

// ---------------------------------------------------------------------------
// GAT aggregate (bf16 h, bf16 out), edge loop unrolled x4 for MLP.
// One wave per (n, h), lanes over channels.
// ---------------------------------------------------------------------------
template <int H, int C>
__global__ void gat_aggregate(const ushort* __restrict__ h, const float* __restrict__ a_src,
                              const float* __restrict__ a_dst, const int* __restrict__ row_start,
                              const int* __restrict__ csr_src, const float* __restrict__ bias,
                              ushort* __restrict__ out, int N) {
    int wid = (blockIdx.x * blockDim.x + threadIdx.x) >> 6;
    int lane = threadIdx.x & 63;
    if (wid >= N * H) return;
    int n = wid / H, hh = wid % H;
    float adst = a_dst[n * H + hh];
    int rs = row_start[n], re = row_start[n + 1];

    // ---- pass 1: max (self loop included), unrolled x4
    float e_self = lrelu(a_src[n * H + hh] + adst);
    float m = e_self;
    int i = rs;
    for (; i + 4 <= re; i += 4) {
        int s0 = csr_src[i], s1 = csr_src[i + 1], s2 = csr_src[i + 2], s3 = csr_src[i + 3];
        float e0 = lrelu(a_src[s0 * H + hh] + adst);
        float e1 = lrelu(a_src[s1 * H + hh] + adst);
        float e2 = lrelu(a_src[s2 * H + hh] + adst);
        float e3 = lrelu(a_src[s3 * H + hh] + adst);
        m = fmaxf(m, fmaxf(fmaxf(e0, e1), fmaxf(e2, e3)));
    }
    for (; i < re; ++i) {
        int s = csr_src[i];
        m = fmaxf(m, lrelu(a_src[s * H + hh] + adst));
    }

    constexpr int NJ = (C + 63) / 64;
    float acc[NJ];
    #pragma unroll
    for (int j = 0; j < NJ; ++j) acc[j] = 0.f;
    float ssum = 0.f;

    {   // self loop
        float wgt = __expf(e_self - m);
        ssum += wgt;
        const ushort* hp = h + (size_t)n * (H * C) + hh * C;
        #pragma unroll
        for (int j = 0; j < NJ; ++j) {
            int c = j * 64 + lane;
            if (c < C) acc[j] += wgt * b2f(hp[c]);
        }
    }
    // ---- pass 2: weighted gather, unrolled x4 (4 gathers in flight)
    i = rs;
    for (; i + 4 <= re; i += 4) {
        int s0 = csr_src[i], s1 = csr_src[i + 1], s2 = csr_src[i + 2], s3 = csr_src[i + 3];
        float w0 = __expf(lrelu(a_src[s0 * H + hh] + adst) - m);
        float w1 = __expf(lrelu(a_src[s1 * H + hh] + adst) - m);
        float w2 = __expf(lrelu(a_src[s2 * H + hh] + adst) - m);
        float w3 = __expf(lrelu(a_src[s3 * H + hh] + adst) - m);
        ssum += (w0 + w1) + (w2 + w3);
        const ushort* p0 = h + (size_t)s0 * (H * C) + hh * C;
        const ushort* p1 = h + (size_t)s1 * (H * C) + hh * C;
        const ushort* p2 = h + (size_t)s2 * (H * C) + hh * C;
        const ushort* p3 = h + (size_t)s3 * (H * C) + hh * C;
        #pragma unroll
        for (int j = 0; j < NJ; ++j) {
            int c = j * 64 + lane;
            if (c < C) {
                float v0 = b2f(p0[c]), v1 = b2f(p1[c]), v2 = b2f(p2[c]), v3 = b2f(p3[c]);
                acc[j] += w0 * v0 + w1 * v1 + w2 * v2 + w3 * v3;
            }
        }
    }
    for (; i < re; ++i) {
        int s = csr_src[i];
        float wgt = __expf(lrelu(a_src[s * H + hh] + adst) - m);
        ssum += wgt;
        const ushort* hp = h + (size_t)s * (H * C) + hh * C;
        #pragma unroll
        for (int j = 0; j < NJ; ++j) {
            int c = j * 64 + lane;
            if (c < C) acc[j] += wgt * b2f(hp[c]);
        }
    }
    float inv = 1.f / (ssum + 1e-16f);
    ushort* op = out + (size_t)n * (H * C) + hh * C;
    #pragma unroll
    for (int j = 0; j < NJ; ++j) {
        int c = j * 64 + lane;
        if (c < C) {
            float v = acc[j] * inv + bias[hh * C + c];
            op[c] = f2b(v > 0.f ? v : 0.f);
        }
    }
}

// ---------------------------------------------------------------------------
// global_add_pool: 2 nodes per wave (32 lanes each over 32 channels)
// ---------------------------------------------------------------------------
__global__ void pool_kernel(const ushort* __restrict__ x, const int* __restrict__ batch,
                            float* __restrict__ g, int N) {
    int wid = (blockIdx.x * blockDim.x + threadIdx.x) >> 6;
    int lane = threadIdx.x & 63;
    int node = wid * 2 + (lane >> 5);
    if (node >= N) return;
    int c = lane & 31;
    int b = batch[node];
    atomicAdd(&g[b * 32 + c], b2f(x[(size_t)node * 32 + c]));
}

__global__ void mlp1_kernel(const float* __restrict__ g, const float* __restrict__ w,
                            const float* __restrict__ b, float* __restrict__ hid) {
    int idx = blockIdx.x * blockDim.x + threadIdx.x;
    if (idx >= NG * 1024) return;
    int gr = idx >> 10, o = idx & 1023;
    float s = b[o];
    const float* gp = g + gr * 32;
    const float* wp = w + o * 32;
    #pragma unroll
    for (int k = 0; k < 32; ++k) s += gp[k] * wp[k];
    hid[idx] = s > 0.f ? s : 0.f;
}

__global__ void mlp2_kernel(const float* __restrict__ hid, const float* __restrict__ w2,
                            const float* __restrict__ b2, float* __restrict__ outp) {
    int wid = (blockIdx.x * blockDim.x + threadIdx.x) >> 6;
    int lane = threadIdx.x & 63;
    if (wid >= NG) return;
    float s = 0.f;
    for (int k = lane; k < 1024; k += 64) s += hid[wid * 1024 + k] * w2[k];
    for (int off = 32; off; off >>= 1) s += __shfl_down(s, off);
    if (lane == 0) outp[wid] = 1.f / (1.f + expf(-(s + b2[0])));
}

// ---------------------------------------------------------------------------
static inline size_t al256(size_t x) { return (x + 255) & ~(size_t)255; }

extern "C" void kernel_launch(void* const* d_in, const int* in_sizes, int n_in,
                              void* d_out, int out_size, void* d_ws, size_t ws_size,
                              hipStream_t stream) {
    const float* x      = (const float*)d_in[0];
    const float* W1     = (const float*)d_in[1];
    const float* as1    = (const float*)d_in[2];
    const float* ad1    = (const float*)d_in[3];
    const float* b1     = (const float*)d_in[4];
    const float* W2     = (const float*)d_in[5];
    const float* as2    = (const float*)d_in[6];
    const float* ad2    = (const float*)d_in[7];
    const float* b2     = (const float*)d_in[8];
    const float* W3     = (const float*)d_in[9];
    const float* as3    = (const float*)d_in[10];
    const float* ad3    = (const float*)d_in[11];
    const float* b3     = (const float*)d_in[12];
    const float* lin_w  = (const float*)d_in[13];
    const float* lin_b  = (const float*)d_in[14];
    const float* lin2_w = (const float*)d_in[15];
    const float* lin2_b = (const float*)d_in[16];
    const int*   ei     = (const int*)d_in[17];
    const int*   batch  = (const int*)d_in[18];
    float* outp = (float*)d_out;

    const int E = in_sizes[17] / 2;
    const int* e_src = ei;
    const int* e_dst = ei + E;

    // workspace carve-up (bf16 node buffers)
    char* p = (char*)d_ws;
    ushort* h_bf   = (ushort*)p; p += al256((size_t)NN * 480 * 2);
    ushort* o_bf   = (ushort*)p; p += al256((size_t)NN * 480 * 2);
    ushort* x_bf   = (ushort*)p; p += al256((size_t)NN * 64 * 2);
    ushort* w1_bf  = (ushort*)p; p += al256((size_t)320 * 64 * 2);
    ushort* w2_bf  = (ushort*)p; p += al256((size_t)480 * 320 * 2);
    ushort* w3_bf  = (ushort*)p; p += al256((size_t)32 * 480 * 2);
    float* asrc    = (float*)p; p += al256((size_t)NN * 5 * 4);
    float* adst    = (float*)p; p += al256((size_t)NN * 5 * 4);
    int*   row_st  = (int*)p;   p += al256((size_t)(NN + 1) * 4);
    int*   cnt     = (int*)p;   p += al256((size_t)NN * 4);   // reused as cursor
    int*   csr_src = (int*)p;   p += al256((size_t)NE * 4);
    float* gpool   = (float*)p; p += al256((size_t)NG * 32 * 4);
    float* hidden  = (float*)p; p += al256((size_t)NG * 1024 * 4);
    (void)ws_size; (void)n_in; (void)out_size;

    dim3 blk(256);

    // ---- CSR build ----
    hipMemsetAsync(cnt, 0, NN * 4, stream);
    count_kernel<<<(E + 255) / 256, 256, 0, stream>>>(e_dst, cnt, E);
    scan_kernel<<<1, 1024, 0, stream>>>(cnt, row_st, NN);
    hipMemsetAsync(cnt, 0, NN * 4, stream);
    fill_kernel<<<(E + 255) / 256, 256, 0, stream>>>(e_src, e_dst, row_st, cnt, csr_src, E);

    // ---- converts ----
    f2b_kernel<<<(NN * 64 + 255) / 256, blk, 0, stream>>>(x, x_bf, NN * 64);
    f2b_kernel<<<(320 * 64 + 255) / 256, blk, 0, stream>>>(W1, w1_bf, 320 * 64);
    f2b_kernel<<<(480 * 320 + 255) / 256, blk, 0, stream>>>(W2, w2_bf, 480 * 320);
    f2b_kernel<<<(32 * 480 + 255) / 256, blk, 0, stream>>>(W3, w3_bf, 32 * 480);

    const int MB = (NN + 63) / 64;   // 313
    // ---- layer 1: K=64 -> H=5, C=64 (width 320) ----
    {
        dim3 g(320 / 32, MB);
        gemm_mfma_kernel<<<g, blk, 0, stream>>>(x_bf, w1_bf, h_bf, NN, 320, 64);
        int waves = NN * 5;
        att_kernel<5, 64><<<(waves * 64 + 255) / 256, blk, 0, stream>>>(h_bf, as1, ad1, asrc, adst, NN);
        gat_aggregate<5, 64><<<(waves * 64 + 255) / 256, blk, 0, stream>>>(h_bf, asrc, adst, row_st, csr_src, b1, o_bf, NN);
    }
    // ---- layer 2: K=320 -> H=5, C=96 (width 480) ----
    {
        dim3 g(480 / 32, MB);
        gemm_mfma_kernel<<<g, blk, 0, stream>>>(o_bf, w2_bf, h_bf, NN, 480, 320);
        int waves = NN * 5;
        att_kernel<5, 96><<<(waves * 64 + 255) / 256, blk, 0, stream>>>(h_bf, as2, ad2, asrc, adst, NN);
        gat_aggregate<5, 96><<<(waves * 64 + 255) / 256, blk, 0, stream>>>(h_bf, asrc, adst, row_st, csr_src, b2, o_bf, NN);
    }
    // ---- layer 3: K=480 -> H=1, C=32 (width 32) ----
    {
        dim3 g(32 / 32, MB);
        gemm_mfma_kernel<<<g, blk, 0, stream>>>(o_bf, w3_bf, h_bf, NN, 32, 480);
        int waves = NN;
        att_kernel<1, 32><<<(waves * 64 + 255) / 256, blk, 0, stream>>>(h_bf, as3, ad3, asrc, adst, NN);
        gat_aggregate<1, 32><<<(waves * 64 + 255) / 256, blk, 0, stream>>>(h_bf, asrc, adst, row_st, csr_src, b3, o_bf, NN);
    }
    // ---- pool + MLP ----
    hipMemsetAsync(gpool, 0, NG * 32 * 4, stream);
    pool_kernel<<<(NN / 2 * 64 + 255) / 256, blk, 0, stream>>>(o_bf, batch, gpool, NN);
    mlp1_kernel<<<(NG * 1024 + 255) / 256, blk, 0, stream>>>(gpool, lin_w, lin_b, hidden);
    mlp2_kernel<<<(NG * 64 + 255) / 256, blk, 0, stream>>>(hidden, lin2_w, lin2_b, outp);
}

// Round 4
// 328.092 us; speedup vs baseline: 3.0821x; 1.5670x over previous
//
#include <hip/hip_runtime.h>
#include <math.h>

#define NN 20000
#define NE 320000
#define NG 128

typedef short short8 __attribute__((ext_vector_type(8)));
typedef float f32x4 __attribute__((ext_vector_type(4)));
typedef float f32x4v __attribute__((ext_vector_type(4)));
typedef unsigned short ushort;
typedef unsigned short ushort4v __attribute__((ext_vector_type(4)));
typedef float float4v __attribute__((ext_vector_type(4)));

__device__ __forceinline__ float b2f(ushort u) {
    unsigned int v = ((unsigned int)u) << 16;
    return __uint_as_float(v);
}
__device__ __forceinline__ ushort f2b(float f) {
    unsigned int u = __float_as_uint(f);
    u = (u + 0x7fff + ((u >> 16) & 1)) >> 16;   // RNE
    return (ushort)u;
}
__device__ __forceinline__ float lrelu(float x) { return x >= 0.f ? x : 0.2f * x; }

// ---------------------------------------------------------------------------
// fused f32 -> bf16 convert of x, W1, W2, W3 (one launch, float4 vectorized)
// ---------------------------------------------------------------------------
#define CVT_N0 (NN * 64 / 4)
#define CVT_N1 (320 * 64 / 4)
#define CVT_N2 (480 * 320 / 4)
#define CVT_N3 (32 * 480 / 4)
__global__ void f2b4_kernel(const float* __restrict__ a0, ushort* __restrict__ o0,
                            const float* __restrict__ a1, ushort* __restrict__ o1,
                            const float* __restrict__ a2, ushort* __restrict__ o2,
                            const float* __restrict__ a3, ushort* __restrict__ o3) {
    int i = blockIdx.x * blockDim.x + threadIdx.x;
    const float* src; ushort* dst; int li;
    if (i < CVT_N0) { src = a0; dst = o0; li = i; }
    else if (i < CVT_N0 + CVT_N1) { src = a1; dst = o1; li = i - CVT_N0; }
    else if (i < CVT_N0 + CVT_N1 + CVT_N2) { src = a2; dst = o2; li = i - CVT_N0 - CVT_N1; }
    else if (i < CVT_N0 + CVT_N1 + CVT_N2 + CVT_N3) { src = a3; dst = o3; li = i - CVT_N0 - CVT_N1 - CVT_N2; }
    else return;
    float4v v = *(const float4v*)(src + (size_t)li * 4);
    ushort4v r;
    r.x = f2b(v.x); r.y = f2b(v.y); r.z = f2b(v.z); r.w = f2b(v.w);
    *(ushort4v*)(dst + (size_t)li * 4) = r;
}

// ---------------------------------------------------------------------------
// CSR build: count -> exclusive scan -> fill
// ---------------------------------------------------------------------------
__global__ void count_kernel(const int* __restrict__ dst, int* __restrict__ cnt, int E) {
    int i = blockIdx.x * blockDim.x + threadIdx.x;
    if (i < E) atomicAdd(&cnt[dst[i]], 1);
}

__global__ __launch_bounds__(1024) void scan_kernel(const int* __restrict__ cnt,
                                                    int* __restrict__ row_start, int n) {
    __shared__ int sh[1024];
    __shared__ int carry;
    int tid = threadIdx.x;
    if (tid == 0) carry = 0;
    __syncthreads();
    for (int base = 0; base < n; base += 1024) {
        int v = (base + tid < n) ? cnt[base + tid] : 0;
        sh[tid] = v;
        __syncthreads();
        for (int off = 1; off < 1024; off <<= 1) {
            int t = (tid >= off) ? sh[tid - off] : 0;
            __syncthreads();
            sh[tid] += t;
            __syncthreads();
        }
        int incl = sh[tid];
        int c0 = carry;
        int tot = sh[1023];
        __syncthreads();
        if (base + tid < n) row_start[base + tid] = c0 + incl - v;
        if (tid == 0) carry = c0 + tot;
        __syncthreads();
    }
    if (tid == 0) row_start[n] = carry;
}

__global__ void fill_kernel(const int* __restrict__ src, const int* __restrict__ dst,
                            const int* __restrict__ row_start, int* __restrict__ cursor,
                            int* __restrict__ csr_src, int E) {
    int i = blockIdx.x * blockDim.x + threadIdx.x;
    if (i < E) {
        int d = dst[i];
        int pos = atomicAdd(&cursor[d], 1);
        csr_src[row_start[d] + pos] = src[i];
    }
}

// ---------------------------------------------------------------------------
// MFMA GEMM: C[m,n] = sum_k A[m,k]*B[n,k], A/B bf16 row-major, C bf16.
// ---------------------------------------------------------------------------
__global__ __launch_bounds__(256) void gemm_mfma_kernel(const ushort* __restrict__ A,
                                                        const ushort* __restrict__ B,
                                                        ushort* __restrict__ C,
                                                        int M, int N, int K) {
    const int tid = threadIdx.x;
    const int w = tid >> 6;
    const int lane = tid & 63;
    const int l15 = lane & 15;
    const int lhi = lane >> 4;           // 0..3
    const int bm = blockIdx.y * 64;
    const int bn = blockIdx.x * 32;

    int arow = bm + w * 16 + l15;
    if (arow >= M) arow = M - 1;         // clamp; stores are masked
    const ushort* ap = A + (size_t)arow * K + lhi * 8;
    const ushort* bp0 = B + (size_t)(bn + l15) * K + lhi * 8;
    const ushort* bp1 = B + (size_t)(bn + 16 + l15) * K + lhi * 8;

    f32x4 acc0 = {0.f, 0.f, 0.f, 0.f};
    f32x4 acc1 = {0.f, 0.f, 0.f, 0.f};
    for (int k0 = 0; k0 < K; k0 += 32) {
        short8 a  = *(const short8*)(ap + k0);
        short8 b0 = *(const short8*)(bp0 + k0);
        short8 b1 = *(const short8*)(bp1 + k0);
        acc0 = __builtin_amdgcn_mfma_f32_16x16x32_bf16(a, b0, acc0, 0, 0, 0);
        acc1 = __builtin_amdgcn_mfma_f32_16x16x32_bf16(a, b1, acc1, 0, 0, 0);
    }
    #pragma unroll
    for (int j = 0; j < 4; ++j) {
        int row = bm + w * 16 + lhi * 4 + j;
        if (row < M) {
            C[(size_t)row * N + bn + l15]      = f2b(acc0[j]);
            C[(size_t)row * N + bn + 16 + l15] = f2b(acc1[j]);
        }
    }
}

// ---------------------------------------------------------------------------
// Attention scalars from bf16 h. One wave per (n, h).
// ---------------------------------------------------------------------------
template <int H, int C>
__global__ void att_kernel(const ushort* __restrict__ h, const float* __restrict__ att_src,
                           const float* __restrict__ att_dst, float* __restrict__ a_src,
                           float* __restrict__ a_dst, int N) {
    int wid = (blockIdx.x * blockDim.x + threadIdx.x) >> 6;
    int lane = threadIdx.x & 63;
    if (wid >= N * H) return;
    int n = wid / H, hh = wid % H;
    const ushort* hp = h + (size_t)n * (H * C) + hh * C;
    float s1 = 0.f, s2 = 0.f;
    for (int c = lane; c < C; c += 64) {
        float v = b2f(hp[c]);
        s1 += v * att_src[hh * C + c];
        s2 += v * att_dst[hh * C + c];
    }
    for (int off = 32; off; off >>= 1) {
        s1 += __shfl_down(s1, off);
        s2 += __shfl_down(s2, off);
    }
    if (lane == 0) { a_src[wid] = s1; a_dst[wid] = s2; }
}

// ---------------------------------------------------------------------------
// Fused GAT aggregate: ONE WAVE PER NODE, all heads, online softmax,
// short8 (16B) vectorized row gathers. Lane l handles channels [8l, 8l+8)
// of the H*C-wide row; its head is hd = 8l / C (requires C % 8 == 0).
// Per-head online-softmax state (m, ssum) is kept redundantly in each lane
// of that head's group -> no cross-lane communication at all.
// ---------------------------------------------------------------------------
template <int H, int C>
__global__ void gat_fused_agg(const ushort* __restrict__ h, const float* __restrict__ a_src,
                              const float* __restrict__ a_dst, const int* __restrict__ row_start,
                              const int* __restrict__ csr_src, const float* __restrict__ bias,
                              ushort* __restrict__ out, int N) {
    constexpr int W = H * C;         // row width (bf16 elements)
    constexpr int VL = W / 8;        // active lanes (40 or 60)
    int n = (blockIdx.x * blockDim.x + threadIdx.x) >> 6;
    int lane = threadIdx.x & 63;
    if (n >= N) return;
    bool act = lane < VL;
    int l = act ? lane : 0;
    int hd = (8 * l) / C;
    float adst = a_dst[n * H + hd];

    // self loop initializes the online state (weight exp(0)=1)
    float m = lrelu(a_src[n * H + hd] + adst);
    float ssum = 1.f;
    float acc[8];
    {
        short8 r = *(const short8*)(h + (size_t)n * W + 8 * l);
        #pragma unroll
        for (int j = 0; j < 8; ++j) acc[j] = b2f((ushort)r[j]);
    }

    int rs = row_start[n], re = row_start[n + 1];
    int i = rs;
    for (; i + 4 <= re; i += 4) {
        int s0 = csr_src[i], s1 = csr_src[i + 1], s2 = csr_src[i + 2], s3 = csr_src[i + 3];
        short8 r0 = *(const short8*)(h + (size_t)s0 * W + 8 * l);
        short8 r1 = *(const short8*)(h + (size_t)s1 * W + 8 * l);
        short8 r2 = *(const short8*)(h + (size_t)s2 * W + 8 * l);
        short8 r3 = *(const short8*)(h + (size_t)s3 * W + 8 * l);
        float e0 = lrelu(a_src[s0 * H + hd] + adst);
        float e1 = lrelu(a_src[s1 * H + hd] + adst);
        float e2 = lrelu(a_src[s2 * H + hd] + adst);
        float e3 = lrelu(a_src[s3 * H + hd] + adst);
        float nm = fmaxf(fmaxf(fmaxf(e0, e1), fmaxf(e2, e3)), m);
        float scale = __expf(m - nm);          // ==1 when nm==m
        m = nm;
        float w0 = __expf(e0 - m), w1 = __expf(e1 - m);
        float w2 = __expf(e2 - m), w3 = __expf(e3 - m);
        ssum = ssum * scale + ((w0 + w1) + (w2 + w3));
        #pragma unroll
        for (int j = 0; j < 8; ++j) {
            float t = w0 * b2f((ushort)r0[j]) + w1 * b2f((ushort)r1[j])
                    + w2 * b2f((ushort)r2[j]) + w3 * b2f((ushort)r3[j]);
            acc[j] = acc[j] * scale + t;
        }
    }
    for (; i < re; ++i) {
        int s = csr_src[i];
        short8 r = *(const short8*)(h + (size_t)s * W + 8 * l);
        float e = lrelu(a_src[s * H + hd] + adst);
        float nm = fmaxf(m, e);
        float scale = __expf(m - nm);
        m = nm;
        float w = __expf(e - nm);
        ssum = ssum * scale + w;
        #pragma unroll
        for (int j = 0; j < 8; ++j) acc[j] = acc[j] * scale + w * b2f((ushort)r[j]);
    }

    float inv = 1.f / (ssum + 1e-16f);
    if (act) {
        short8 o;
        #pragma unroll
        for (int j = 0; j < 8; ++j) {
            float v = acc[j] * inv + bias[8 * l + j];
            o[j] = (short)f2b(v > 0.f ? v : 0.f);
        }
        *(short8*)(out + (size_t)n * W + 8 * l) = o;
    }
}

// ---------------------------------------------------------------------------
// Layer-3 aggregate (H=1, C=32, row = 64B): one wave per node, 16 edge
// groups x 4 lanes (short8 each). Online softmax per group, merged at the
// end with a shfl_xor butterfly (online-softmax merge).
// ---------------------------------------------------------------------------
__global__ void gat_agg_c32(const ushort* __restrict__ h, const float* __restrict__ a_src,
                            const float* __restrict__ a_dst, const int* __restrict__ row_start,
                            const int* __restrict__ csr_src, const float* __restrict__ bias,
                            ushort* __restrict__ out, int N) {
    int n = (blockIdx.x * blockDim.x + threadIdx.x) >> 6;
    int lane = threadIdx.x & 63;
    if (n >= N) return;
    int g = lane >> 2;      // edge group 0..15
    int q = lane & 3;       // row chunk: channels [8q, 8q+8)
    float adst = a_dst[n];
    int rs = row_start[n];
    int total = row_start[n + 1] - rs + 1;   // + self loop (k==0)

    float m = -1e30f, ssum = 0.f;
    float acc[8];
    #pragma unroll
    for (int j = 0; j < 8; ++j) acc[j] = 0.f;

    for (int k = g; k < total; k += 16) {
        int s = (k == 0) ? n : csr_src[rs + k - 1];
        float e = lrelu(a_src[s] + adst);
        float nm = fmaxf(m, e);
        float scale = __expf(m - nm);        // m=-1e30 -> 0
        m = nm;
        float w = __expf(e - nm);
        ssum = ssum * scale + w;
        short8 r = *(const short8*)(h + (size_t)s * 32 + 8 * q);
        #pragma unroll
        for (int j = 0; j < 8; ++j) acc[j] = acc[j] * scale + w * b2f((ushort)r[j]);
    }

    // merge the 16 groups (butterfly over lane strides 4,8,16,32)
    #pragma unroll
    for (int off = 4; off < 64; off <<= 1) {
        float m2 = __shfl_xor(m, off);
        float s2 = __shfl_xor(ssum, off);
        float nm = fmaxf(m, m2);
        float sc1 = __expf(m - nm), sc2 = __expf(m2 - nm);
        ssum = ssum * sc1 + s2 * sc2;
        #pragma unroll
        for (int j = 0; j < 8; ++j) {
            float a2 = __shfl_xor(acc[j], off);
            acc[j] = acc[j] * sc1 + a2 * sc2;
        }
        m = nm;
    }

    if (lane < 4) {
        float inv = 1.f / (ssum + 1e-16f);
        short8 o;
        #pragma unroll
        for (int j = 0; j < 8; ++j) {
            float v = acc[j] * inv + bias[8 * lane + j];
            o[j] = (short)f2b(v > 0.f ? v : 0.f);
        }
        *(short8*)(out + (size_t)n * 32 + 8 * lane) = o;
    }
}

// ---------------------------------------------------------------------------
// global_add_pool: 2 nodes per wave (32 lanes each over 32 channels)
// ---------------------------------------------------------------------------
__global__ void pool_kernel(const ushort* __restrict__ x, const int* __restrict__ batch,
                            float* __restrict__ g, int N) {
    int wid = (blockIdx.x * blockDim.x + threadIdx.x) >> 6;
    int lane = threadIdx.x & 63;
    int node = wid * 2 + (lane >> 5);
    if (node >= N) return;
    int c = lane & 31;
    int b = batch[node];
    atomicAdd(&g[b * 32 + c], b2f(x[(size_t)node * 32 + c]));
}

__global__ void mlp1_kernel(const float* __restrict__ g, const float* __restrict__ w,
                            const float* __restrict__ b, float* __restrict__ hid) {
    int idx = blockIdx.x * blockDim.x + threadIdx.x;
    if (idx >= NG * 1024) return;
    int gr = idx >> 10, o = idx & 1023;
    float s = b[o];
    const float* gp = g + gr * 32;
    const float* wp = w + o * 32;
    #pragma unroll
    for (int k = 0; k < 32; ++k) s += gp[k] * wp[k];
    hid[idx] = s > 0.f ? s : 0.f;
}

__global__ void mlp2_kernel(const float* __restrict__ hid, const float* __restrict__ w2,
                            const float* __restrict__ b2, float* __restrict__ outp) {
    int wid = (blockIdx.x * blockDim.x + threadIdx.x) >> 6;
    int lane = threadIdx.x & 63;
    if (wid >= NG) return;
    float s = 0.f;
    for (int k = lane; k < 1024; k += 64) s += hid[wid * 1024 + k] * w2[k];
    for (int off = 32; off; off >>= 1) s += __shfl_down(s, off);
    if (lane == 0) outp[wid] = 1.f / (1.f + expf(-(s + b2[0])));
}

// ---------------------------------------------------------------------------
static inline size_t al256(size_t x) { return (x + 255) & ~(size_t)255; }

extern "C" void kernel_launch(void* const* d_in, const int* in_sizes, int n_in,
                              void* d_out, int out_size, void* d_ws, size_t ws_size,
                              hipStream_t stream) {
    const float* x      = (const float*)d_in[0];
    const float* W1     = (const float*)d_in[1];
    const float* as1    = (const float*)d_in[2];
    const float* ad1    = (const float*)d_in[3];
    const float* b1     = (const float*)d_in[4];
    const float* W2     = (const float*)d_in[5];
    const float* as2    = (const float*)d_in[6];
    const float* ad2    = (const float*)d_in[7];
    const float* b2     = (const float*)d_in[8];
    const float* W3     = (const float*)d_in[9];
    const float* as3    = (const float*)d_in[10];
    const float* ad3    = (const float*)d_in[11];
    const float* b3     = (const float*)d_in[12];
    const float* lin_w  = (const float*)d_in[13];
    const float* lin_b  = (const float*)d_in[14];
    const float* lin2_w = (const float*)d_in[15];
    const float* lin2_b = (const float*)d_in[16];
    const int*   ei     = (const int*)d_in[17];
    const int*   batch  = (const int*)d_in[18];
    float* outp = (float*)d_out;

    const int E = in_sizes[17] / 2;
    const int* e_src = ei;
    const int* e_dst = ei + E;

    // workspace carve-up (bf16 node buffers)
    char* p = (char*)d_ws;
    ushort* h_bf   = (ushort*)p; p += al256((size_t)NN * 480 * 2);
    ushort* o_bf   = (ushort*)p; p += al256((size_t)NN * 480 * 2);
    ushort* x_bf   = (ushort*)p; p += al256((size_t)NN * 64 * 2);
    ushort* w1_bf  = (ushort*)p; p += al256((size_t)320 * 64 * 2);
    ushort* w2_bf  = (ushort*)p; p += al256((size_t)480 * 320 * 2);
    ushort* w3_bf  = (ushort*)p; p += al256((size_t)32 * 480 * 2);
    float* asrc    = (float*)p; p += al256((size_t)NN * 5 * 4);
    float* adst    = (float*)p; p += al256((size_t)NN * 5 * 4);
    int*   row_st  = (int*)p;   p += al256((size_t)(NN + 1) * 4);
    int*   cnt     = (int*)p;   p += al256((size_t)NN * 4);   // reused as cursor
    int*   csr_src = (int*)p;   p += al256((size_t)NE * 4);
    float* gpool   = (float*)p; p += al256((size_t)NG * 32 * 4);
    float* hidden  = (float*)p; p += al256((size_t)NG * 1024 * 4);
    (void)ws_size; (void)n_in; (void)out_size;

    dim3 blk(256);

    // ---- CSR build ----
    hipMemsetAsync(cnt, 0, NN * 4, stream);
    count_kernel<<<(E + 255) / 256, 256, 0, stream>>>(e_dst, cnt, E);
    scan_kernel<<<1, 1024, 0, stream>>>(cnt, row_st, NN);
    hipMemsetAsync(cnt, 0, NN * 4, stream);
    fill_kernel<<<(E + 255) / 256, 256, 0, stream>>>(e_src, e_dst, row_st, cnt, csr_src, E);

    // ---- converts (single launch) ----
    {
        int tot = CVT_N0 + CVT_N1 + CVT_N2 + CVT_N3;
        f2b4_kernel<<<(tot + 255) / 256, blk, 0, stream>>>(x, x_bf, W1, w1_bf, W2, w2_bf, W3, w3_bf);
    }

    const int MB = (NN + 63) / 64;   // 313
    const int NBLK = (NN + 3) / 4;   // one wave per node, 4 waves/block
    // ---- layer 1: K=64 -> H=5, C=64 (width 320) ----
    {
        dim3 g(320 / 32, MB);
        gemm_mfma_kernel<<<g, blk, 0, stream>>>(x_bf, w1_bf, h_bf, NN, 320, 64);
        int waves = NN * 5;
        att_kernel<5, 64><<<(waves * 64 + 255) / 256, blk, 0, stream>>>(h_bf, as1, ad1, asrc, adst, NN);
        gat_fused_agg<5, 64><<<NBLK, blk, 0, stream>>>(h_bf, asrc, adst, row_st, csr_src, b1, o_bf, NN);
    }
    // ---- layer 2: K=320 -> H=5, C=96 (width 480) ----
    {
        dim3 g(480 / 32, MB);
        gemm_mfma_kernel<<<g, blk, 0, stream>>>(o_bf, w2_bf, h_bf, NN, 480, 320);
        int waves = NN * 5;
        att_kernel<5, 96><<<(waves * 64 + 255) / 256, blk, 0, stream>>>(h_bf, as2, ad2, asrc, adst, NN);
        gat_fused_agg<5, 96><<<NBLK, blk, 0, stream>>>(h_bf, asrc, adst, row_st, csr_src, b2, o_bf, NN);
    }
    // ---- layer 3: K=480 -> H=1, C=32 (width 32) ----
    {
        dim3 g(32 / 32, MB);
        gemm_mfma_kernel<<<g, blk, 0, stream>>>(o_bf, w3_bf, h_bf, NN, 32, 480);
        att_kernel<1, 32><<<(NN * 64 + 255) / 256, blk, 0, stream>>>(h_bf, as3, ad3, asrc, adst, NN);
        gat_agg_c32<<<NBLK, blk, 0, stream>>>(h_bf, asrc, adst, row_st, csr_src, b3, o_bf, NN);
    }
    // ---- pool + MLP ----
    hipMemsetAsync(gpool, 0, NG * 32 * 4, stream);
    pool_kernel<<<(NN / 2 * 64 + 255) / 256, blk, 0, stream>>>(o_bf, batch, gpool, NN);
    mlp1_kernel<<<(NG * 1024 + 255) / 256, blk, 0, stream>>>(gpool, lin_w, lin_b, hidden);
    mlp2_kernel<<<(NG * 64 + 255) / 256, blk, 0, stream>>>(hidden, lin2_w, lin2_b, outp);
}

// Round 5
// 319.482 us; speedup vs baseline: 3.1652x; 1.0269x over previous
//
#include <hip/hip_runtime.h>
#include <math.h>

#define NN 20000
#define NE 320000
#define NG 128

typedef short short8 __attribute__((ext_vector_type(8)));
typedef float f32x4 __attribute__((ext_vector_type(4)));
typedef unsigned short ushort;
typedef unsigned short ushort4v __attribute__((ext_vector_type(4)));
typedef float float4v __attribute__((ext_vector_type(4)));

__device__ __forceinline__ float b2f(ushort u) {
    unsigned int v = ((unsigned int)u) << 16;
    return __uint_as_float(v);
}
__device__ __forceinline__ ushort f2b(float f) {
    unsigned int u = __float_as_uint(f);
    u = (u + 0x7fff + ((u >> 16) & 1)) >> 16;   // RNE
    return (ushort)u;
}
__device__ __forceinline__ float lrelu(float x) { return x >= 0.f ? x : 0.2f * x; }

// ---------------------------------------------------------------------------
// fused f32 -> bf16 convert of x, W1, W2, W3 (one launch, float4 vectorized)
// ---------------------------------------------------------------------------
#define CVT_N0 (NN * 64 / 4)
#define CVT_N1 (320 * 64 / 4)
#define CVT_N2 (480 * 320 / 4)
#define CVT_N3 (32 * 480 / 4)
__global__ void f2b4_kernel(const float* __restrict__ a0, ushort* __restrict__ o0,
                            const float* __restrict__ a1, ushort* __restrict__ o1,
                            const float* __restrict__ a2, ushort* __restrict__ o2,
                            const float* __restrict__ a3, ushort* __restrict__ o3) {
    int i = blockIdx.x * blockDim.x + threadIdx.x;
    const float* src; ushort* dst; int li;
    if (i < CVT_N0) { src = a0; dst = o0; li = i; }
    else if (i < CVT_N0 + CVT_N1) { src = a1; dst = o1; li = i - CVT_N0; }
    else if (i < CVT_N0 + CVT_N1 + CVT_N2) { src = a2; dst = o2; li = i - CVT_N0 - CVT_N1; }
    else if (i < CVT_N0 + CVT_N1 + CVT_N2 + CVT_N3) { src = a3; dst = o3; li = i - CVT_N0 - CVT_N1 - CVT_N2; }
    else return;
    float4v v = *(const float4v*)(src + (size_t)li * 4);
    ushort4v r;
    r.x = f2b(v.x); r.y = f2b(v.y); r.z = f2b(v.z); r.w = f2b(v.w);
    *(ushort4v*)(dst + (size_t)li * 4) = r;
}

// ---------------------------------------------------------------------------
// CSR build: count -> exclusive scan -> fill
// ---------------------------------------------------------------------------
__global__ void count_kernel(const int* __restrict__ dst, int* __restrict__ cnt, int E) {
    int i = blockIdx.x * blockDim.x + threadIdx.x;
    if (i < E) atomicAdd(&cnt[dst[i]], 1);
}

__global__ __launch_bounds__(1024) void scan_kernel(const int* __restrict__ cnt,
                                                    int* __restrict__ row_start, int n) {
    __shared__ int sh[1024];
    __shared__ int carry;
    int tid = threadIdx.x;
    if (tid == 0) carry = 0;
    __syncthreads();
    for (int base = 0; base < n; base += 1024) {
        int v = (base + tid < n) ? cnt[base + tid] : 0;
        sh[tid] = v;
        __syncthreads();
        for (int off = 1; off < 1024; off <<= 1) {
            int t = (tid >= off) ? sh[tid - off] : 0;
            __syncthreads();
            sh[tid] += t;
            __syncthreads();
        }
        int incl = sh[tid];
        int c0 = carry;
        int tot = sh[1023];
        __syncthreads();
        if (base + tid < n) row_start[base + tid] = c0 + incl - v;
        if (tid == 0) carry = c0 + tot;
        __syncthreads();
    }
    if (tid == 0) row_start[n] = carry;
}

__global__ void fill_kernel(const int* __restrict__ src, const int* __restrict__ dst,
                            const int* __restrict__ row_start, int* __restrict__ cursor,
                            int* __restrict__ csr_src, int E) {
    int i = blockIdx.x * blockDim.x + threadIdx.x;
    if (i < E) {
        int d = dst[i];
        int pos = atomicAdd(&cursor[d], 1);
        csr_src[row_start[d] + pos] = src[i];
    }
}

// ---------------------------------------------------------------------------
// MFMA GEMM, templated on K (full unroll) and NF (16-col fragments/wave).
// C[m,n] = sum_k A[m,k]*B[n,k]; A MxK, B NxK row-major bf16; C bf16.
// Block = 4 waves stacked on rows: 64 rows x NF*16 cols per block.
// 1-D grid, row-panel-major, bijective XCD chunk swizzle so each XCD owns
// contiguous complete row panels (A fetched ~once from HBM).
// ---------------------------------------------------------------------------
template <int K, int NF>
__global__ __launch_bounds__(256) void gemm_tmpl(const ushort* __restrict__ A,
                                                 const ushort* __restrict__ B,
                                                 ushort* __restrict__ C,
                                                 int M, int N, int gridx) {
    const int nwg = gridDim.x;
    int bid = blockIdx.x;
    // bijective XCD chunk swizzle (m204)
    {
        int q = nwg >> 3, r = nwg & 7;
        int xcd = bid & 7, idx = bid >> 3;
        bid = (xcd < r ? xcd * (q + 1) : r * (q + 1) + (xcd - r) * q) + idx;
    }
    const int by = bid / gridx;          // row panel (64 rows)
    const int bx = bid % gridx;          // col tile (NF*16 cols)

    const int tid = threadIdx.x;
    const int w = tid >> 6;
    const int lane = tid & 63;
    const int l15 = lane & 15;
    const int lhi = lane >> 4;           // 0..3

    const int bm = by * 64 + w * 16;
    const int bn = bx * (NF * 16);

    int arow = bm + l15;
    if (arow >= M) arow = M - 1;         // clamp; stores masked
    const ushort* ap = A + (size_t)arow * K + lhi * 8;

    const ushort* bp[NF];
    #pragma unroll
    for (int f = 0; f < NF; ++f) {
        int brow = bn + f * 16 + l15;
        if (brow >= N) brow = N - 1;     // clamp; stores masked
        bp[f] = B + (size_t)brow * K + lhi * 8;
    }

    f32x4 acc[NF];
    #pragma unroll
    for (int f = 0; f < NF; ++f) acc[f] = (f32x4){0.f, 0.f, 0.f, 0.f};

    #pragma unroll
    for (int k0 = 0; k0 < K; k0 += 32) {
        short8 a = *(const short8*)(ap + k0);
        #pragma unroll
        for (int f = 0; f < NF; ++f) {
            short8 b = *(const short8*)(bp[f] + k0);
            acc[f] = __builtin_amdgcn_mfma_f32_16x16x32_bf16(a, b, acc[f], 0, 0, 0);
        }
    }

    #pragma unroll
    for (int f = 0; f < NF; ++f) {
        #pragma unroll
        for (int j = 0; j < 4; ++j) {
            int row = bm + lhi * 4 + j;
            int col = bn + f * 16 + l15;
            if (row < M && col < N) C[(size_t)row * N + col] = f2b(acc[f][j]);
        }
    }
}

// ---------------------------------------------------------------------------
// Attention scalars from bf16 h. One wave per (n, h).
// ---------------------------------------------------------------------------
template <int H, int C>
__global__ void att_kernel(const ushort* __restrict__ h, const float* __restrict__ att_src,
                           const float* __restrict__ att_dst, float* __restrict__ a_src,
                           float* __restrict__ a_dst, int N) {
    int wid = (blockIdx.x * blockDim.x + threadIdx.x) >> 6;
    int lane = threadIdx.x & 63;
    if (wid >= N * H) return;
    int n = wid / H, hh = wid % H;
    const ushort* hp = h + (size_t)n * (H * C) + hh * C;
    float s1 = 0.f, s2 = 0.f;
    for (int c = lane; c < C; c += 64) {
        float v = b2f(hp[c]);
        s1 += v * att_src[hh * C + c];
        s2 += v * att_dst[hh * C + c];
    }
    for (int off = 32; off; off >>= 1) {
        s1 += __shfl_down(s1, off);
        s2 += __shfl_down(s2, off);
    }
    if (lane == 0) { a_src[wid] = s1; a_dst[wid] = s2; }
}

// ---------------------------------------------------------------------------
// Fused GAT aggregate: ONE WAVE PER NODE, all heads, online softmax,
// short8 (16B) vectorized row gathers. Lane l handles channels [8l, 8l+8).
// ---------------------------------------------------------------------------
template <int H, int C>
__global__ void gat_fused_agg(const ushort* __restrict__ h, const float* __restrict__ a_src,
                              const float* __restrict__ a_dst, const int* __restrict__ row_start,
                              const int* __restrict__ csr_src, const float* __restrict__ bias,
                              ushort* __restrict__ out, int N) {
    constexpr int W = H * C;         // row width (bf16 elements)
    constexpr int VL = W / 8;        // active lanes (40 or 60)
    int n = (blockIdx.x * blockDim.x + threadIdx.x) >> 6;
    int lane = threadIdx.x & 63;
    if (n >= N) return;
    bool act = lane < VL;
    int l = act ? lane : 0;
    int hd = (8 * l) / C;
    float adst = a_dst[n * H + hd];

    // self loop initializes the online state (weight exp(0)=1)
    float m = lrelu(a_src[n * H + hd] + adst);
    float ssum = 1.f;
    float acc[8];
    {
        short8 r = *(const short8*)(h + (size_t)n * W + 8 * l);
        #pragma unroll
        for (int j = 0; j < 8; ++j) acc[j] = b2f((ushort)r[j]);
    }

    int rs = row_start[n], re = row_start[n + 1];
    int i = rs;
    for (; i + 4 <= re; i += 4) {
        int s0 = csr_src[i], s1 = csr_src[i + 1], s2 = csr_src[i + 2], s3 = csr_src[i + 3];
        short8 r0 = *(const short8*)(h + (size_t)s0 * W + 8 * l);
        short8 r1 = *(const short8*)(h + (size_t)s1 * W + 8 * l);
        short8 r2 = *(const short8*)(h + (size_t)s2 * W + 8 * l);
        short8 r3 = *(const short8*)(h + (size_t)s3 * W + 8 * l);
        float e0 = lrelu(a_src[s0 * H + hd] + adst);
        float e1 = lrelu(a_src[s1 * H + hd] + adst);
        float e2 = lrelu(a_src[s2 * H + hd] + adst);
        float e3 = lrelu(a_src[s3 * H + hd] + adst);
        float nm = fmaxf(fmaxf(fmaxf(e0, e1), fmaxf(e2, e3)), m);
        float scale = __expf(m - nm);          // ==1 when nm==m
        m = nm;
        float w0 = __expf(e0 - m), w1 = __expf(e1 - m);
        float w2 = __expf(e2 - m), w3 = __expf(e3 - m);
        ssum = ssum * scale + ((w0 + w1) + (w2 + w3));
        #pragma unroll
        for (int j = 0; j < 8; ++j) {
            float t = w0 * b2f((ushort)r0[j]) + w1 * b2f((ushort)r1[j])
                    + w2 * b2f((ushort)r2[j]) + w3 * b2f((ushort)r3[j]);
            acc[j] = acc[j] * scale + t;
        }
    }
    for (; i < re; ++i) {
        int s = csr_src[i];
        short8 r = *(const short8*)(h + (size_t)s * W + 8 * l);
        float e = lrelu(a_src[s * H + hd] + adst);
        float nm = fmaxf(m, e);
        float scale = __expf(m - nm);
        m = nm;
        float w = __expf(e - nm);
        ssum = ssum * scale + w;
        #pragma unroll
        for (int j = 0; j < 8; ++j) acc[j] = acc[j] * scale + w * b2f((ushort)r[j]);
    }

    float inv = 1.f / (ssum + 1e-16f);
    if (act) {
        short8 o;
        #pragma unroll
        for (int j = 0; j < 8; ++j) {
            float v = acc[j] * inv + bias[8 * l + j];
            o[j] = (short)f2b(v > 0.f ? v : 0.f);
        }
        *(short8*)(out + (size_t)n * W + 8 * l) = o;
    }
}

// ---------------------------------------------------------------------------
// Layer-3 aggregate (H=1, C=32): one wave per node, 16 edge groups x 4 lanes.
// ---------------------------------------------------------------------------
__global__ void gat_agg_c32(const ushort* __restrict__ h, const float* __restrict__ a_src,
                            const float* __restrict__ a_dst, const int* __restrict__ row_start,
                            const int* __restrict__ csr_src, const float* __restrict__ bias,
                            ushort* __restrict__ out, int N) {
    int n = (blockIdx.x * blockDim.x + threadIdx.x) >> 6;
    int lane = threadIdx.x & 63;
    if (n >= N) return;
    int g = lane >> 2;      // edge group 0..15
    int q = lane & 3;       // row chunk: channels [8q, 8q+8)
    float adst = a_dst[n];
    int rs = row_start[n];
    int total = row_start[n + 1] - rs + 1;   // + self loop (k==0)

    float m = -1e30f, ssum = 0.f;
    float acc[8];
    #pragma unroll
    for (int j = 0; j < 8; ++j) acc[j] = 0.f;

    for (int k = g; k < total; k += 16) {
        int s = (k == 0) ? n : csr_src[rs + k - 1];
        float e = lrelu(a_src[s] + adst);
        float nm = fmaxf(m, e);
        float scale = __expf(m - nm);        // m=-1e30 -> 0
        m = nm;
        float w = __expf(e - nm);
        ssum = ssum * scale + w;
        short8 r = *(const short8*)(h + (size_t)s * 32 + 8 * q);
        #pragma unroll
        for (int j = 0; j < 8; ++j) acc[j] = acc[j] * scale + w * b2f((ushort)r[j]);
    }

    // merge the 16 groups (butterfly over lane strides 4,8,16,32)
    #pragma unroll
    for (int off = 4; off < 64; off <<= 1) {
        float m2 = __shfl_xor(m, off);
        float s2 = __shfl_xor(ssum, off);
        float nm = fmaxf(m, m2);
        float sc1 = __expf(m - nm), sc2 = __expf(m2 - nm);
        ssum = ssum * sc1 + s2 * sc2;
        #pragma unroll
        for (int j = 0; j < 8; ++j) {
            float a2 = __shfl_xor(acc[j], off);
            acc[j] = acc[j] * sc1 + a2 * sc2;
        }
        m = nm;
    }

    if (lane < 4) {
        float inv = 1.f / (ssum + 1e-16f);
        short8 o;
        #pragma unroll
        for (int j = 0; j < 8; ++j) {
            float v = acc[j] * inv + bias[8 * lane + j];
            o[j] = (short)f2b(v > 0.f ? v : 0.f);
        }
        *(short8*)(out + (size_t)n * 32 + 8 * lane) = o;
    }
}

// ---------------------------------------------------------------------------
// global_add_pool: 2 nodes per wave (32 lanes each over 32 channels)
// ---------------------------------------------------------------------------
__global__ void pool_kernel(const ushort* __restrict__ x, const int* __restrict__ batch,
                            float* __restrict__ g, int N) {
    int wid = (blockIdx.x * blockDim.x + threadIdx.x) >> 6;
    int lane = threadIdx.x & 63;
    int node = wid * 2 + (lane >> 5);
    if (node >= N) return;
    int c = lane & 31;
    int b = batch[node];
    atomicAdd(&g[b * 32 + c], b2f(x[(size_t)node * 32 + c]));
}

__global__ void mlp1_kernel(const float* __restrict__ g, const float* __restrict__ w,
                            const float* __restrict__ b, float* __restrict__ hid) {
    int idx = blockIdx.x * blockDim.x + threadIdx.x;
    if (idx >= NG * 1024) return;
    int gr = idx >> 10, o = idx & 1023;
    float s = b[o];
    const float* gp = g + gr * 32;
    const float* wp = w + o * 32;
    #pragma unroll
    for (int k = 0; k < 32; ++k) s += gp[k] * wp[k];
    hid[idx] = s > 0.f ? s : 0.f;
}

__global__ void mlp2_kernel(const float* __restrict__ hid, const float* __restrict__ w2,
                            const float* __restrict__ b2, float* __restrict__ outp) {
    int wid = (blockIdx.x * blockDim.x + threadIdx.x) >> 6;
    int lane = threadIdx.x & 63;
    if (wid >= NG) return;
    float s = 0.f;
    for (int k = lane; k < 1024; k += 64) s += hid[wid * 1024 + k] * w2[k];
    for (int off = 32; off; off >>= 1) s += __shfl_down(s, off);
    if (lane == 0) outp[wid] = 1.f / (1.f + expf(-(s + b2[0])));
}

// ---------------------------------------------------------------------------
static inline size_t al256(size_t x) { return (x + 255) & ~(size_t)255; }

extern "C" void kernel_launch(void* const* d_in, const int* in_sizes, int n_in,
                              void* d_out, int out_size, void* d_ws, size_t ws_size,
                              hipStream_t stream) {
    const float* x      = (const float*)d_in[0];
    const float* W1     = (const float*)d_in[1];
    const float* as1    = (const float*)d_in[2];
    const float* ad1    = (const float*)d_in[3];
    const float* b1     = (const float*)d_in[4];
    const float* W2     = (const float*)d_in[5];
    const float* as2    = (const float*)d_in[6];
    const float* ad2    = (const float*)d_in[7];
    const float* b2     = (const float*)d_in[8];
    const float* W3     = (const float*)d_in[9];
    const float* as3    = (const float*)d_in[10];
    const float* ad3    = (const float*)d_in[11];
    const float* b3     = (const float*)d_in[12];
    const float* lin_w  = (const float*)d_in[13];
    const float* lin_b  = (const float*)d_in[14];
    const float* lin2_w = (const float*)d_in[15];
    const float* lin2_b = (const float*)d_in[16];
    const int*   ei     = (const int*)d_in[17];
    const int*   batch  = (const int*)d_in[18];
    float* outp = (float*)d_out;

    const int E = in_sizes[17] / 2;
    const int* e_src = ei;
    const int* e_dst = ei + E;

    // workspace carve-up (bf16 node buffers)
    char* p = (char*)d_ws;
    ushort* h_bf   = (ushort*)p; p += al256((size_t)NN * 480 * 2);
    ushort* o_bf   = (ushort*)p; p += al256((size_t)NN * 480 * 2);
    ushort* x_bf   = (ushort*)p; p += al256((size_t)NN * 64 * 2);
    ushort* w1_bf  = (ushort*)p; p += al256((size_t)320 * 64 * 2);
    ushort* w2_bf  = (ushort*)p; p += al256((size_t)480 * 320 * 2);
    ushort* w3_bf  = (ushort*)p; p += al256((size_t)32 * 480 * 2);
    float* asrc    = (float*)p; p += al256((size_t)NN * 5 * 4);
    float* adst    = (float*)p; p += al256((size_t)NN * 5 * 4);
    int*   row_st  = (int*)p;   p += al256((size_t)(NN + 1) * 4);
    int*   cnt     = (int*)p;   p += al256((size_t)NN * 4);   // reused as cursor
    int*   csr_src = (int*)p;   p += al256((size_t)NE * 4);
    float* gpool   = (float*)p; p += al256((size_t)NG * 32 * 4);
    float* hidden  = (float*)p; p += al256((size_t)NG * 1024 * 4);
    (void)ws_size; (void)n_in; (void)out_size;

    dim3 blk(256);

    // ---- CSR build ----
    hipMemsetAsync(cnt, 0, NN * 4, stream);
    count_kernel<<<(E + 255) / 256, 256, 0, stream>>>(e_dst, cnt, E);
    scan_kernel<<<1, 1024, 0, stream>>>(cnt, row_st, NN);
    hipMemsetAsync(cnt, 0, NN * 4, stream);
    fill_kernel<<<(E + 255) / 256, 256, 0, stream>>>(e_src, e_dst, row_st, cnt, csr_src, E);

    // ---- converts (single launch) ----
    {
        int tot = CVT_N0 + CVT_N1 + CVT_N2 + CVT_N3;
        f2b4_kernel<<<(tot + 255) / 256, blk, 0, stream>>>(x, x_bf, W1, w1_bf, W2, w2_bf, W3, w3_bf);
    }

    const int MPAN = (NN + 63) / 64;     // 313 row panels
    const int NBLK = (NN + 3) / 4;       // aggregate: one wave per node
    // ---- layer 1: K=64 -> H=5, C=64 (width 320) ----
    {
        int gx = (320 + 127) / 128;      // 3
        gemm_tmpl<64, 8><<<gx * MPAN, blk, 0, stream>>>(x_bf, w1_bf, h_bf, NN, 320, gx);
        int waves = NN * 5;
        att_kernel<5, 64><<<(waves * 64 + 255) / 256, blk, 0, stream>>>(h_bf, as1, ad1, asrc, adst, NN);
        gat_fused_agg<5, 64><<<NBLK, blk, 0, stream>>>(h_bf, asrc, adst, row_st, csr_src, b1, o_bf, NN);
    }
    // ---- layer 2: K=320 -> H=5, C=96 (width 480) ----
    {
        int gx = (480 + 127) / 128;      // 4
        gemm_tmpl<320, 8><<<gx * MPAN, blk, 0, stream>>>(o_bf, w2_bf, h_bf, NN, 480, gx);
        int waves = NN * 5;
        att_kernel<5, 96><<<(waves * 64 + 255) / 256, blk, 0, stream>>>(h_bf, as2, ad2, asrc, adst, NN);
        gat_fused_agg<5, 96><<<NBLK, blk, 0, stream>>>(h_bf, asrc, adst, row_st, csr_src, b2, o_bf, NN);
    }
    // ---- layer 3: K=480 -> H=1, C=32 (width 32) ----
    {
        int gx = 1;                      // NF=2 -> 32 cols
        gemm_tmpl<480, 2><<<gx * MPAN, blk, 0, stream>>>(o_bf, w3_bf, h_bf, NN, 32, gx);
        att_kernel<1, 32><<<(NN * 64 + 255) / 256, blk, 0, stream>>>(h_bf, as3, ad3, asrc, adst, NN);
        gat_agg_c32<<<NBLK, blk, 0, stream>>>(h_bf, asrc, adst, row_st, csr_src, b3, o_bf, NN);
    }
    // ---- pool + MLP ----
    hipMemsetAsync(gpool, 0, NG * 32 * 4, stream);
    pool_kernel<<<(NN / 2 * 64 + 255) / 256, blk, 0, stream>>>(o_bf, batch, gpool, NN);
    mlp1_kernel<<<(NG * 1024 + 255) / 256, blk, 0, stream>>>(gpool, lin_w, lin_b, hidden);
    mlp2_kernel<<<(NG * 64 + 255) / 256, blk, 0, stream>>>(hidden, lin2_w, lin2_b, outp);
}

// Round 6
// 289.264 us; speedup vs baseline: 3.4958x; 1.1045x over previous
//
#include <hip/hip_runtime.h>
#include <math.h>

#define NN 20000
#define NE 320000
#define NG 128

typedef short short8 __attribute__((ext_vector_type(8)));
typedef float f32x4 __attribute__((ext_vector_type(4)));
typedef unsigned short ushort;
typedef unsigned short ushort4v __attribute__((ext_vector_type(4)));
typedef float float4v __attribute__((ext_vector_type(4)));

__device__ __forceinline__ float b2f(ushort u) {
    unsigned int v = ((unsigned int)u) << 16;
    return __uint_as_float(v);
}
__device__ __forceinline__ ushort f2b(float f) {
    unsigned int u = __float_as_uint(f);
    u = (u + 0x7fff + ((u >> 16) & 1)) >> 16;   // RNE
    return (ushort)u;
}
__device__ __forceinline__ float lrelu(float x) { return x >= 0.f ? x : 0.2f * x; }

// ---------------------------------------------------------------------------
// fused f32 -> bf16 convert of x, W1, W2, W3 (one launch, float4 vectorized)
// ---------------------------------------------------------------------------
#define CVT_N0 (NN * 64 / 4)
#define CVT_N1 (320 * 64 / 4)
#define CVT_N2 (480 * 320 / 4)
#define CVT_N3 (32 * 480 / 4)
__global__ void f2b4_kernel(const float* __restrict__ a0, ushort* __restrict__ o0,
                            const float* __restrict__ a1, ushort* __restrict__ o1,
                            const float* __restrict__ a2, ushort* __restrict__ o2,
                            const float* __restrict__ a3, ushort* __restrict__ o3) {
    int i = blockIdx.x * blockDim.x + threadIdx.x;
    const float* src; ushort* dst; int li;
    if (i < CVT_N0) { src = a0; dst = o0; li = i; }
    else if (i < CVT_N0 + CVT_N1) { src = a1; dst = o1; li = i - CVT_N0; }
    else if (i < CVT_N0 + CVT_N1 + CVT_N2) { src = a2; dst = o2; li = i - CVT_N0 - CVT_N1; }
    else if (i < CVT_N0 + CVT_N1 + CVT_N2 + CVT_N3) { src = a3; dst = o3; li = i - CVT_N0 - CVT_N1 - CVT_N2; }
    else return;
    float4v v = *(const float4v*)(src + (size_t)li * 4);
    ushort4v r;
    r.x = f2b(v.x); r.y = f2b(v.y); r.z = f2b(v.z); r.w = f2b(v.w);
    *(ushort4v*)(dst + (size_t)li * 4) = r;
}

// ---------------------------------------------------------------------------
// CSR build: count -> exclusive scan -> fill
// ---------------------------------------------------------------------------
__global__ void count_kernel(const int* __restrict__ dst, int* __restrict__ cnt, int E) {
    int i = blockIdx.x * blockDim.x + threadIdx.x;
    if (i < E) atomicAdd(&cnt[dst[i]], 1);
}

__global__ __launch_bounds__(1024) void scan_kernel(const int* __restrict__ cnt,
                                                    int* __restrict__ row_start, int n) {
    __shared__ int sh[1024];
    __shared__ int carry;
    int tid = threadIdx.x;
    if (tid == 0) carry = 0;
    __syncthreads();
    for (int base = 0; base < n; base += 1024) {
        int v = (base + tid < n) ? cnt[base + tid] : 0;
        sh[tid] = v;
        __syncthreads();
        for (int off = 1; off < 1024; off <<= 1) {
            int t = (tid >= off) ? sh[tid - off] : 0;
            __syncthreads();
            sh[tid] += t;
            __syncthreads();
        }
        int incl = sh[tid];
        int c0 = carry;
        int tot = sh[1023];
        __syncthreads();
        if (base + tid < n) row_start[base + tid] = c0 + incl - v;
        if (tid == 0) carry = c0 + tot;
        __syncthreads();
    }
    if (tid == 0) row_start[n] = carry;
}

__global__ void fill_kernel(const int* __restrict__ src, const int* __restrict__ dst,
                            const int* __restrict__ row_start, int* __restrict__ cursor,
                            int* __restrict__ csr_src, int E) {
    int i = blockIdx.x * blockDim.x + threadIdx.x;
    if (i < E) {
        int d = dst[i];
        int pos = atomicAdd(&cursor[d], 1);
        csr_src[row_start[d] + pos] = src[i];
    }
}

// ---------------------------------------------------------------------------
// MFMA GEMM with LDS-staged B panel + explicit register double-buffering.
// C[m,n] = sum_k A[m,k]*B[n,k]; A MxK, B NxK row-major bf16; C bf16.
// Block = 256 threads = 4 waves. Block tile: 64 rows x BN cols (BN = NF*16).
// B panel (BN x K, row-padded +8 bf16 -> stride == 4 mod 32 banks: 2-way,
// free) staged in LDS ONCE per block. K is compile-time -> full unroll with
// a_cur/a_nxt, b_cur/b_nxt reg double-buffer (loads of step k+1 issue before
// MFMAs of step k). Requires N % BN == 0.
// 1-D grid, row-panel-major, bijective XCD chunk swizzle (A locality per XCD).
// ---------------------------------------------------------------------------
template <int K, int NF>
__global__ __launch_bounds__(256) void gemm_lds(const ushort* __restrict__ A,
                                                const ushort* __restrict__ B,
                                                ushort* __restrict__ C,
                                                int M, int N, int gridx) {
    constexpr int BN = NF * 16;
    constexpr int KP = K + 8;            // padded row (bf16 elems), 16B-aligned
    constexpr int KS = K / 32;           // k-steps
    __shared__ ushort Bs[BN][KP];

    const int nwg = gridDim.x;
    int bid = blockIdx.x;
    {   // bijective XCD chunk swizzle (m204)
        int q = nwg >> 3, r = nwg & 7;
        int xcd = bid & 7, idx = bid >> 3;
        bid = (xcd < r ? xcd * (q + 1) : r * (q + 1) + (xcd - r) * q) + idx;
    }
    const int by = bid / gridx;          // row panel (64 rows)
    const int bx = bid % gridx;          // col tile (BN cols)
    const int bn = bx * BN;

    const int tid = threadIdx.x;
    const int w = tid >> 6;
    const int lane = tid & 63;
    const int l15 = lane & 15;
    const int lhi = lane >> 4;           // 0..3

    // ---- stage B panel (BN x K) into LDS, short8 chunks ----
    constexpr int NCH = BN * (K / 8);
    for (int i = tid; i < NCH; i += 256) {
        int r = i / (K / 8), c8 = i % (K / 8);
        short8 v = *(const short8*)(B + (size_t)(bn + r) * K + c8 * 8);
        *(short8*)(&Bs[r][c8 * 8]) = v;
    }
    __syncthreads();

    const int bm = by * 64 + w * 16;
    int arow = bm + l15;
    if (arow >= M) arow = M - 1;         // clamp; stores masked
    const ushort* ap = A + (size_t)arow * K + lhi * 8;

    f32x4 acc[NF];
    #pragma unroll
    for (int f = 0; f < NF; ++f) acc[f] = (f32x4){0.f, 0.f, 0.f, 0.f};

    short8 a_cur = *(const short8*)ap;
    short8 b_cur[NF], b_nxt[NF];
    #pragma unroll
    for (int f = 0; f < NF; ++f)
        b_cur[f] = *(const short8*)(&Bs[f * 16 + l15][lhi * 8]);

    #pragma unroll
    for (int ks = 0; ks < KS; ++ks) {
        short8 a_nxt = a_cur;
        if (ks + 1 < KS) {
            a_nxt = *(const short8*)(ap + (ks + 1) * 32);
            #pragma unroll
            for (int f = 0; f < NF; ++f)
                b_nxt[f] = *(const short8*)(&Bs[f * 16 + l15][(ks + 1) * 32 + lhi * 8]);
        }
        #pragma unroll
        for (int f = 0; f < NF; ++f)
            acc[f] = __builtin_amdgcn_mfma_f32_16x16x32_bf16(a_cur, b_cur[f], acc[f], 0, 0, 0);
        a_cur = a_nxt;
        #pragma unroll
        for (int f = 0; f < NF; ++f) b_cur[f] = b_nxt[f];
    }

    #pragma unroll
    for (int f = 0; f < NF; ++f) {
        #pragma unroll
        for (int j = 0; j < 4; ++j) {
            int row = bm + lhi * 4 + j;
            if (row < M) C[(size_t)row * N + bn + f * 16 + l15] = f2b(acc[f][j]);
        }
    }
}

// ---------------------------------------------------------------------------
// Attention scalars from bf16 h. One wave per (n, h); short8 vector loads,
// C/8 active lanes, 16-lane shuffle reduce.
// ---------------------------------------------------------------------------
template <int H, int C>
__global__ void att_kernel(const ushort* __restrict__ h, const float* __restrict__ att_src,
                           const float* __restrict__ att_dst, float* __restrict__ a_src,
                           float* __restrict__ a_dst, int N) {
    constexpr int VL = C / 8;            // 8, 12, or 4 active lanes
    int wid = (blockIdx.x * blockDim.x + threadIdx.x) >> 6;
    int lane = threadIdx.x & 63;
    if (wid >= N * H) return;
    int n = wid / H, hh = wid % H;
    float s1 = 0.f, s2 = 0.f;
    if (lane < VL) {
        short8 r = *(const short8*)(h + (size_t)n * (H * C) + hh * C + lane * 8);
        const float* asp = att_src + hh * C + lane * 8;
        const float* adp = att_dst + hh * C + lane * 8;
        #pragma unroll
        for (int j = 0; j < 8; ++j) {
            float v = b2f((ushort)r[j]);
            s1 += v * asp[j];
            s2 += v * adp[j];
        }
    }
    #pragma unroll
    for (int off = 8; off; off >>= 1) {
        s1 += __shfl_down(s1, off);
        s2 += __shfl_down(s2, off);
    }
    if (lane == 0) { a_src[wid] = s1; a_dst[wid] = s2; }
}

// ---------------------------------------------------------------------------
// Fused GAT aggregate: ONE WAVE PER NODE, all heads, online softmax,
// short8 (16B) vectorized row gathers. Lane l handles channels [8l, 8l+8).
// ---------------------------------------------------------------------------
template <int H, int C>
__global__ void gat_fused_agg(const ushort* __restrict__ h, const float* __restrict__ a_src,
                              const float* __restrict__ a_dst, const int* __restrict__ row_start,
                              const int* __restrict__ csr_src, const float* __restrict__ bias,
                              ushort* __restrict__ out, int N) {
    constexpr int W = H * C;         // row width (bf16 elements)
    constexpr int VL = W / 8;        // active lanes (40 or 60)
    int n = (blockIdx.x * blockDim.x + threadIdx.x) >> 6;
    int lane = threadIdx.x & 63;
    if (n >= N) return;
    bool act = lane < VL;
    int l = act ? lane : 0;
    int hd = (8 * l) / C;
    float adst = a_dst[n * H + hd];

    // self loop initializes the online state (weight exp(0)=1)
    float m = lrelu(a_src[n * H + hd] + adst);
    float ssum = 1.f;
    float acc[8];
    {
        short8 r = *(const short8*)(h + (size_t)n * W + 8 * l);
        #pragma unroll
        for (int j = 0; j < 8; ++j) acc[j] = b2f((ushort)r[j]);
    }

    int rs = row_start[n], re = row_start[n + 1];
    int i = rs;
    for (; i + 4 <= re; i += 4) {
        int s0 = csr_src[i], s1 = csr_src[i + 1], s2 = csr_src[i + 2], s3 = csr_src[i + 3];
        short8 r0 = *(const short8*)(h + (size_t)s0 * W + 8 * l);
        short8 r1 = *(const short8*)(h + (size_t)s1 * W + 8 * l);
        short8 r2 = *(const short8*)(h + (size_t)s2 * W + 8 * l);
        short8 r3 = *(const short8*)(h + (size_t)s3 * W + 8 * l);
        float e0 = lrelu(a_src[s0 * H + hd] + adst);
        float e1 = lrelu(a_src[s1 * H + hd] + adst);
        float e2 = lrelu(a_src[s2 * H + hd] + adst);
        float e3 = lrelu(a_src[s3 * H + hd] + adst);
        float nm = fmaxf(fmaxf(fmaxf(e0, e1), fmaxf(e2, e3)), m);
        float scale = __expf(m - nm);          // ==1 when nm==m
        m = nm;
        float w0 = __expf(e0 - m), w1 = __expf(e1 - m);
        float w2 = __expf(e2 - m), w3 = __expf(e3 - m);
        ssum = ssum * scale + ((w0 + w1) + (w2 + w3));
        #pragma unroll
        for (int j = 0; j < 8; ++j) {
            float t = w0 * b2f((ushort)r0[j]) + w1 * b2f((ushort)r1[j])
                    + w2 * b2f((ushort)r2[j]) + w3 * b2f((ushort)r3[j]);
            acc[j] = acc[j] * scale + t;
        }
    }
    for (; i < re; ++i) {
        int s = csr_src[i];
        short8 r = *(const short8*)(h + (size_t)s * W + 8 * l);
        float e = lrelu(a_src[s * H + hd] + adst);
        float nm = fmaxf(m, e);
        float scale = __expf(m - nm);
        m = nm;
        float w = __expf(e - nm);
        ssum = ssum * scale + w;
        #pragma unroll
        for (int j = 0; j < 8; ++j) acc[j] = acc[j] * scale + w * b2f((ushort)r[j]);
    }

    float inv = 1.f / (ssum + 1e-16f);
    if (act) {
        short8 o;
        #pragma unroll
        for (int j = 0; j < 8; ++j) {
            float v = acc[j] * inv + bias[8 * l + j];
            o[j] = (short)f2b(v > 0.f ? v : 0.f);
        }
        *(short8*)(out + (size_t)n * W + 8 * l) = o;
    }
}

// ---------------------------------------------------------------------------
// Layer-3 aggregate (H=1, C=32): one wave per node, 16 edge groups x 4 lanes.
// ---------------------------------------------------------------------------
__global__ void gat_agg_c32(const ushort* __restrict__ h, const float* __restrict__ a_src,
                            const float* __restrict__ a_dst, const int* __restrict__ row_start,
                            const int* __restrict__ csr_src, const float* __restrict__ bias,
                            ushort* __restrict__ out, int N) {
    int n = (blockIdx.x * blockDim.x + threadIdx.x) >> 6;
    int lane = threadIdx.x & 63;
    if (n >= N) return;
    int g = lane >> 2;      // edge group 0..15
    int q = lane & 3;       // row chunk: channels [8q, 8q+8)
    float adst = a_dst[n];
    int rs = row_start[n];
    int total = row_start[n + 1] - rs + 1;   // + self loop (k==0)

    float m = -1e30f, ssum = 0.f;
    float acc[8];
    #pragma unroll
    for (int j = 0; j < 8; ++j) acc[j] = 0.f;

    for (int k = g; k < total; k += 16) {
        int s = (k == 0) ? n : csr_src[rs + k - 1];
        float e = lrelu(a_src[s] + adst);
        float nm = fmaxf(m, e);
        float scale = __expf(m - nm);        // m=-1e30 -> 0
        m = nm;
        float w = __expf(e - nm);
        ssum = ssum * scale + w;
        short8 r = *(const short8*)(h + (size_t)s * 32 + 8 * q);
        #pragma unroll
        for (int j = 0; j < 8; ++j) acc[j] = acc[j] * scale + w * b2f((ushort)r[j]);
    }

    // merge the 16 groups (butterfly over lane strides 4,8,16,32)
    #pragma unroll
    for (int off = 4; off < 64; off <<= 1) {
        float m2 = __shfl_xor(m, off);
        float s2 = __shfl_xor(ssum, off);
        float nm = fmaxf(m, m2);
        float sc1 = __expf(m - nm), sc2 = __expf(m2 - nm);
        ssum = ssum * sc1 + s2 * sc2;
        #pragma unroll
        for (int j = 0; j < 8; ++j) {
            float a2 = __shfl_xor(acc[j], off);
            acc[j] = acc[j] * sc1 + a2 * sc2;
        }
        m = nm;
    }

    if (lane < 4) {
        float inv = 1.f / (ssum + 1e-16f);
        short8 o;
        #pragma unroll
        for (int j = 0; j < 8; ++j) {
            float v = acc[j] * inv + bias[8 * lane + j];
            o[j] = (short)f2b(v > 0.f ? v : 0.f);
        }
        *(short8*)(out + (size_t)n * 32 + 8 * lane) = o;
    }
}

// ---------------------------------------------------------------------------
// global_add_pool: 2 nodes per wave (32 lanes each over 32 channels)
// ---------------------------------------------------------------------------
__global__ void pool_kernel(const ushort* __restrict__ x, const int* __restrict__ batch,
                            float* __restrict__ g, int N) {
    int wid = (blockIdx.x * blockDim.x + threadIdx.x) >> 6;
    int lane = threadIdx.x & 63;
    int node = wid * 2 + (lane >> 5);
    if (node >= N) return;
    int c = lane & 31;
    int b = batch[node];
    atomicAdd(&g[b * 32 + c], b2f(x[(size_t)node * 32 + c]));
}

__global__ void mlp1_kernel(const float* __restrict__ g, const float* __restrict__ w,
                            const float* __restrict__ b, float* __restrict__ hid) {
    int idx = blockIdx.x * blockDim.x + threadIdx.x;
    if (idx >= NG * 1024) return;
    int gr = idx >> 10, o = idx & 1023;
    float s = b[o];
    const float* gp = g + gr * 32;
    const float* wp = w + o * 32;
    #pragma unroll
    for (int k = 0; k < 32; ++k) s += gp[k] * wp[k];
    hid[idx] = s > 0.f ? s : 0.f;
}

__global__ void mlp2_kernel(const float* __restrict__ hid, const float* __restrict__ w2,
                            const float* __restrict__ b2, float* __restrict__ outp) {
    int wid = (blockIdx.x * blockDim.x + threadIdx.x) >> 6;
    int lane = threadIdx.x & 63;
    if (wid >= NG) return;
    float s = 0.f;
    for (int k = lane; k < 1024; k += 64) s += hid[wid * 1024 + k] * w2[k];
    for (int off = 32; off; off >>= 1) s += __shfl_down(s, off);
    if (lane == 0) outp[wid] = 1.f / (1.f + expf(-(s + b2[0])));
}

// ---------------------------------------------------------------------------
static inline size_t al256(size_t x) { return (x + 255) & ~(size_t)255; }

extern "C" void kernel_launch(void* const* d_in, const int* in_sizes, int n_in,
                              void* d_out, int out_size, void* d_ws, size_t ws_size,
                              hipStream_t stream) {
    const float* x      = (const float*)d_in[0];
    const float* W1     = (const float*)d_in[1];
    const float* as1    = (const float*)d_in[2];
    const float* ad1    = (const float*)d_in[3];
    const float* b1     = (const float*)d_in[4];
    const float* W2     = (const float*)d_in[5];
    const float* as2    = (const float*)d_in[6];
    const float* ad2    = (const float*)d_in[7];
    const float* b2     = (const float*)d_in[8];
    const float* W3     = (const float*)d_in[9];
    const float* as3    = (const float*)d_in[10];
    const float* ad3    = (const float*)d_in[11];
    const float* b3     = (const float*)d_in[12];
    const float* lin_w  = (const float*)d_in[13];
    const float* lin_b  = (const float*)d_in[14];
    const float* lin2_w = (const float*)d_in[15];
    const float* lin2_b = (const float*)d_in[16];
    const int*   ei     = (const int*)d_in[17];
    const int*   batch  = (const int*)d_in[18];
    float* outp = (float*)d_out;

    const int E = in_sizes[17] / 2;
    const int* e_src = ei;
    const int* e_dst = ei + E;

    // workspace carve-up (bf16 node buffers)
    char* p = (char*)d_ws;
    ushort* h_bf   = (ushort*)p; p += al256((size_t)NN * 480 * 2);
    ushort* o_bf   = (ushort*)p; p += al256((size_t)NN * 480 * 2);
    ushort* x_bf   = (ushort*)p; p += al256((size_t)NN * 64 * 2);
    ushort* w1_bf  = (ushort*)p; p += al256((size_t)320 * 64 * 2);
    ushort* w2_bf  = (ushort*)p; p += al256((size_t)480 * 320 * 2);
    ushort* w3_bf  = (ushort*)p; p += al256((size_t)32 * 480 * 2);
    float* asrc    = (float*)p; p += al256((size_t)NN * 5 * 4);
    float* adst    = (float*)p; p += al256((size_t)NN * 5 * 4);
    int*   row_st  = (int*)p;   p += al256((size_t)(NN + 1) * 4);
    int*   cnt     = (int*)p;   p += al256((size_t)NN * 4);   // reused as cursor
    int*   csr_src = (int*)p;   p += al256((size_t)NE * 4);
    float* gpool   = (float*)p; p += al256((size_t)NG * 32 * 4);
    float* hidden  = (float*)p; p += al256((size_t)NG * 1024 * 4);
    (void)ws_size; (void)n_in; (void)out_size;

    dim3 blk(256);

    // ---- CSR build ----
    hipMemsetAsync(cnt, 0, NN * 4, stream);
    count_kernel<<<(E + 255) / 256, 256, 0, stream>>>(e_dst, cnt, E);
    scan_kernel<<<1, 1024, 0, stream>>>(cnt, row_st, NN);
    hipMemsetAsync(cnt, 0, NN * 4, stream);
    fill_kernel<<<(E + 255) / 256, 256, 0, stream>>>(e_src, e_dst, row_st, cnt, csr_src, E);

    // ---- converts (single launch) ----
    {
        int tot = CVT_N0 + CVT_N1 + CVT_N2 + CVT_N3;
        f2b4_kernel<<<(tot + 255) / 256, blk, 0, stream>>>(x, x_bf, W1, w1_bf, W2, w2_bf, W3, w3_bf);
    }

    const int MPAN = (NN + 63) / 64;     // 313 row panels
    const int NBLK = (NN + 3) / 4;       // aggregate: one wave per node
    // ---- layer 1: K=64 -> H=5, C=64 (width 320) ----
    {
        int gx = 320 / 80;               // BN=80 (NF=5) -> 4 col tiles
        gemm_lds<64, 5><<<gx * MPAN, blk, 0, stream>>>(x_bf, w1_bf, h_bf, NN, 320, gx);
        int waves = NN * 5;
        att_kernel<5, 64><<<(waves * 64 + 255) / 256, blk, 0, stream>>>(h_bf, as1, ad1, asrc, adst, NN);
        gat_fused_agg<5, 64><<<NBLK, blk, 0, stream>>>(h_bf, asrc, adst, row_st, csr_src, b1, o_bf, NN);
    }
    // ---- layer 2: K=320 -> H=5, C=96 (width 480) ----
    {
        int gx = 480 / 96;               // BN=96 (NF=6) -> 5 col tiles
        gemm_lds<320, 6><<<gx * MPAN, blk, 0, stream>>>(o_bf, w2_bf, h_bf, NN, 480, gx);
        int waves = NN * 5;
        att_kernel<5, 96><<<(waves * 64 + 255) / 256, blk, 0, stream>>>(h_bf, as2, ad2, asrc, adst, NN);
        gat_fused_agg<5, 96><<<NBLK, blk, 0, stream>>>(h_bf, asrc, adst, row_st, csr_src, b2, o_bf, NN);
    }
    // ---- layer 3: K=480 -> H=1, C=32 (width 32) ----
    {
        int gx = 1;                      // BN=32 (NF=2)
        gemm_lds<480, 2><<<gx * MPAN, blk, 0, stream>>>(o_bf, w3_bf, h_bf, NN, 32, gx);
        att_kernel<1, 32><<<(NN * 64 + 255) / 256, blk, 0, stream>>>(h_bf, as3, ad3, asrc, adst, NN);
        gat_agg_c32<<<NBLK, blk, 0, stream>>>(h_bf, asrc, adst, row_st, csr_src, b3, o_bf, NN);
    }
    // ---- pool + MLP ----
    hipMemsetAsync(gpool, 0, NG * 32 * 4, stream);
    pool_kernel<<<(NN / 2 * 64 + 255) / 256, blk, 0, stream>>>(o_bf, batch, gpool, NN);
    mlp1_kernel<<<(NG * 1024 + 255) / 256, blk, 0, stream>>>(gpool, lin_w, lin_b, hidden);
    mlp2_kernel<<<(NG * 64 + 255) / 256, blk, 0, stream>>>(hidden, lin2_w, lin2_b, outp);
}

// Round 7
// 254.074 us; speedup vs baseline: 3.9800x; 1.1385x over previous
//
#include <hip/hip_runtime.h>
#include <math.h>

#define NN 20000
#define NE 320000
#define NG 128

typedef short short8 __attribute__((ext_vector_type(8)));
typedef float f32x4 __attribute__((ext_vector_type(4)));
typedef float f32x2 __attribute__((ext_vector_type(2)));
typedef unsigned short ushort;
typedef unsigned short ushort4v __attribute__((ext_vector_type(4)));
typedef float float4v __attribute__((ext_vector_type(4)));
typedef unsigned int uint;
typedef unsigned int uint2v __attribute__((ext_vector_type(2)));
typedef unsigned int uint4v __attribute__((ext_vector_type(4)));

__device__ __forceinline__ float b2f(ushort u) {
    unsigned int v = ((unsigned int)u) << 16;
    return __uint_as_float(v);
}
__device__ __forceinline__ ushort f2b(float f) {
    unsigned int u = __float_as_uint(f);
    u = (u + 0x7fff + ((u >> 16) & 1)) >> 16;   // RNE
    return (ushort)u;
}
__device__ __forceinline__ float lrelu(float x) { return x >= 0.f ? x : 0.2f * x; }

// ---------------------------------------------------------------------------
// fused f32 -> bf16 convert of x, W1, W2, W3 (one launch, float4 vectorized)
// ---------------------------------------------------------------------------
#define CVT_N0 (NN * 64 / 4)
#define CVT_N1 (320 * 64 / 4)
#define CVT_N2 (480 * 320 / 4)
#define CVT_N3 (32 * 480 / 4)
__global__ void f2b4_kernel(const float* __restrict__ a0, ushort* __restrict__ o0,
                            const float* __restrict__ a1, ushort* __restrict__ o1,
                            const float* __restrict__ a2, ushort* __restrict__ o2,
                            const float* __restrict__ a3, ushort* __restrict__ o3) {
    int i = blockIdx.x * blockDim.x + threadIdx.x;
    const float* src; ushort* dst; int li;
    if (i < CVT_N0) { src = a0; dst = o0; li = i; }
    else if (i < CVT_N0 + CVT_N1) { src = a1; dst = o1; li = i - CVT_N0; }
    else if (i < CVT_N0 + CVT_N1 + CVT_N2) { src = a2; dst = o2; li = i - CVT_N0 - CVT_N1; }
    else if (i < CVT_N0 + CVT_N1 + CVT_N2 + CVT_N3) { src = a3; dst = o3; li = i - CVT_N0 - CVT_N1 - CVT_N2; }
    else return;
    float4v v = *(const float4v*)(src + (size_t)li * 4);
    ushort4v r;
    r.x = f2b(v.x); r.y = f2b(v.y); r.z = f2b(v.z); r.w = f2b(v.w);
    *(ushort4v*)(dst + (size_t)li * 4) = r;
}

// ---------------------------------------------------------------------------
// bf16 -> fp8 e4m3 convert (8 elems/thread)
// ---------------------------------------------------------------------------
__global__ void b2f8_kernel(const ushort* __restrict__ in, unsigned char* __restrict__ out, int n8) {
    int i = blockIdx.x * blockDim.x + threadIdx.x;
    if (i >= n8) return;
    short8 v = *(const short8*)(in + (size_t)i * 8);
    uint w0 = __builtin_amdgcn_cvt_pk_fp8_f32(b2f((ushort)v[0]), b2f((ushort)v[1]), 0, false);
    w0 = __builtin_amdgcn_cvt_pk_fp8_f32(b2f((ushort)v[2]), b2f((ushort)v[3]), w0, true);
    uint w1 = __builtin_amdgcn_cvt_pk_fp8_f32(b2f((ushort)v[4]), b2f((ushort)v[5]), 0, false);
    w1 = __builtin_amdgcn_cvt_pk_fp8_f32(b2f((ushort)v[6]), b2f((ushort)v[7]), w1, true);
    uint2v o; o.x = w0; o.y = w1;
    *(uint2v*)(out + (size_t)i * 8) = o;
}

// ---------------------------------------------------------------------------
// CSR build: count -> parallel scan -> fill
// ---------------------------------------------------------------------------
__global__ void count_kernel(const int* __restrict__ dst, int* __restrict__ cnt, int E) {
    int i = blockIdx.x * blockDim.x + threadIdx.x;
    if (i < E) atomicAdd(&cnt[dst[i]], 1);
}

// each thread owns 20 contiguous elements; one block-scan of 1024 partials
__global__ __launch_bounds__(1024) void scan_kernel(const int* __restrict__ cnt,
                                                    int* __restrict__ row_start, int n) {
    __shared__ int sh[1024];
    int tid = threadIdx.x;
    int base = tid * 20;
    int local[20];
    int s = 0;
    #pragma unroll
    for (int k = 0; k < 20; ++k) {
        int idx = base + k;
        int v = (idx < n) ? cnt[idx] : 0;
        local[k] = s;           // exclusive within chunk
        s += v;
    }
    sh[tid] = s;
    __syncthreads();
    for (int off = 1; off < 1024; off <<= 1) {
        int t = (tid >= off) ? sh[tid - off] : 0;
        __syncthreads();
        sh[tid] += t;
        __syncthreads();
    }
    int pre = (tid == 0) ? 0 : sh[tid - 1];
    #pragma unroll
    for (int k = 0; k < 20; ++k) {
        int idx = base + k;
        if (idx < n) row_start[idx] = pre + local[k];
    }
    if (tid == 1023) row_start[n] = sh[1023];
}

__global__ void fill_kernel(const int* __restrict__ src, const int* __restrict__ dst,
                            const int* __restrict__ row_start, int* __restrict__ cursor,
                            int* __restrict__ csr_src, int E) {
    int i = blockIdx.x * blockDim.x + threadIdx.x;
    if (i < E) {
        int d = dst[i];
        int pos = atomicAdd(&cursor[d], 1);
        csr_src[row_start[d] + pos] = src[i];
    }
}

// ---------------------------------------------------------------------------
// MFMA GEMM with LDS-staged B panel + reg double-buffering + FUSED per-head
// attention dots in the epilogue (requires BN == C, gridx == H; head = bx).
// C[m,n] = sum_k A[m,k]*B[n,k]; A MxK, B NxK row-major bf16; C bf16.
// a_src[m,h] = dot(C_row_headslice, att_src[h]); same for a_dst (f32, exact).
// ---------------------------------------------------------------------------
template <int K, int NF, int H>
__global__ __launch_bounds__(256) void gemm_lds(const ushort* __restrict__ A,
                                                const ushort* __restrict__ B,
                                                ushort* __restrict__ C,
                                                const float* __restrict__ att_src,
                                                const float* __restrict__ att_dst,
                                                float* __restrict__ a_src,
                                                float* __restrict__ a_dst,
                                                int M, int N, int gridx) {
    constexpr int BN = NF * 16;
    constexpr int KP = K + 8;            // padded row (bf16 elems)
    constexpr int KS = K / 32;           // k-steps
    __shared__ ushort Bs[BN][KP];

    const int nwg = gridDim.x;
    int bid = blockIdx.x;
    {   // bijective XCD chunk swizzle (m204)
        int q = nwg >> 3, r = nwg & 7;
        int xcd = bid & 7, idx = bid >> 3;
        bid = (xcd < r ? xcd * (q + 1) : r * (q + 1) + (xcd - r) * q) + idx;
    }
    const int by = bid / gridx;          // row panel (64 rows)
    const int bx = bid % gridx;          // col tile == head index
    const int bn = bx * BN;

    const int tid = threadIdx.x;
    const int w = tid >> 6;
    const int lane = tid & 63;
    const int l15 = lane & 15;
    const int lhi = lane >> 4;           // 0..3

    // ---- stage B panel (BN x K) into LDS, short8 chunks ----
    constexpr int NCH = BN * (K / 8);
    for (int i = tid; i < NCH; i += 256) {
        int r = i / (K / 8), c8 = i % (K / 8);
        short8 v = *(const short8*)(B + (size_t)(bn + r) * K + c8 * 8);
        *(short8*)(&Bs[r][c8 * 8]) = v;
    }
    __syncthreads();

    const int bm = by * 64 + w * 16;
    int arow = bm + l15;
    if (arow >= M) arow = M - 1;         // clamp; stores masked
    const ushort* ap = A + (size_t)arow * K + lhi * 8;

    f32x4 acc[NF];
    #pragma unroll
    for (int f = 0; f < NF; ++f) acc[f] = (f32x4){0.f, 0.f, 0.f, 0.f};

    short8 a_cur = *(const short8*)ap;
    short8 b_cur[NF], b_nxt[NF];
    #pragma unroll
    for (int f = 0; f < NF; ++f)
        b_cur[f] = *(const short8*)(&Bs[f * 16 + l15][lhi * 8]);

    #pragma unroll
    for (int ks = 0; ks < KS; ++ks) {
        short8 a_nxt = a_cur;
        if (ks + 1 < KS) {
            a_nxt = *(const short8*)(ap + (ks + 1) * 32);
            #pragma unroll
            for (int f = 0; f < NF; ++f)
                b_nxt[f] = *(const short8*)(&Bs[f * 16 + l15][(ks + 1) * 32 + lhi * 8]);
        }
        #pragma unroll
        for (int f = 0; f < NF; ++f)
            acc[f] = __builtin_amdgcn_mfma_f32_16x16x32_bf16(a_cur, b_cur[f], acc[f], 0, 0, 0);
        a_cur = a_nxt;
        #pragma unroll
        for (int f = 0; f < NF; ++f) b_cur[f] = b_nxt[f];
    }

    // ---- C store (bf16) ----
    #pragma unroll
    for (int f = 0; f < NF; ++f) {
        #pragma unroll
        for (int j = 0; j < 4; ++j) {
            int row = bm + lhi * 4 + j;
            if (row < M) C[(size_t)row * N + bn + f * 16 + l15] = f2b(acc[f][j]);
        }
    }

    // ---- fused attention dots (BN == C, head = bx) ----
    float as_v[NF], ad_v[NF];
    #pragma unroll
    for (int f = 0; f < NF; ++f) {
        as_v[f] = att_src[bx * BN + f * 16 + l15];
        ad_v[f] = att_dst[bx * BN + f * 16 + l15];
    }
    #pragma unroll
    for (int j = 0; j < 4; ++j) {
        float ps = 0.f, pd = 0.f;
        #pragma unroll
        for (int f = 0; f < NF; ++f) {
            ps += acc[f][j] * as_v[f];
            pd += acc[f][j] * ad_v[f];
        }
        #pragma unroll
        for (int off = 1; off < 16; off <<= 1) {
            ps += __shfl_xor(ps, off);
            pd += __shfl_xor(pd, off);
        }
        int row = bm + lhi * 4 + j;
        if (l15 == 0 && row < M) {
            a_src[row * H + bx] = ps;
            a_dst[row * H + bx] = pd;
        }
    }
}

// ---------------------------------------------------------------------------
// fp8 GAT aggregate: ONE WAVE PER NODE, all heads, online softmax.
// Lane l handles 16 fp8 channels [16l, 16l+16) via one 16B load; decode with
// cvt_pk_f32_fp8. Out written bf16 (+bias, relu).
// ---------------------------------------------------------------------------
template <int H, int C>
__global__ void gat_agg_f8(const unsigned char* __restrict__ h8,
                           const float* __restrict__ a_src, const float* __restrict__ a_dst,
                           const int* __restrict__ row_start, const int* __restrict__ csr_src,
                           const float* __restrict__ bias, ushort* __restrict__ out, int N) {
    constexpr int W = H * C;         // channels == bytes per row
    constexpr int VL = W / 16;       // active lanes (20 or 30)
    int n = (blockIdx.x * blockDim.x + threadIdx.x) >> 6;
    int lane = threadIdx.x & 63;
    if (n >= N) return;
    bool act = lane < VL;
    int l = act ? lane : 0;
    int hd = (16 * l) / C;
    float adst = a_dst[n * H + hd];

    // self loop initializes online state (weight exp(0)=1)
    float m = lrelu(a_src[n * H + hd] + adst);
    float ssum = 1.f;
    float acc[16];
    {
        uint4v r = *(const uint4v*)(h8 + (size_t)n * W + 16 * l);
        #pragma unroll
        for (int d = 0; d < 4; ++d) {
            f32x2 lo = __builtin_amdgcn_cvt_pk_f32_fp8(r[d], false);
            f32x2 hi = __builtin_amdgcn_cvt_pk_f32_fp8(r[d], true);
            acc[d * 4 + 0] = lo.x; acc[d * 4 + 1] = lo.y;
            acc[d * 4 + 2] = hi.x; acc[d * 4 + 3] = hi.y;
        }
    }

    int rs = row_start[n], re = row_start[n + 1];
    int i = rs;
    for (; i + 4 <= re; i += 4) {
        int s0 = csr_src[i], s1 = csr_src[i + 1], s2 = csr_src[i + 2], s3 = csr_src[i + 3];
        uint4v r0 = *(const uint4v*)(h8 + (size_t)s0 * W + 16 * l);
        uint4v r1 = *(const uint4v*)(h8 + (size_t)s1 * W + 16 * l);
        uint4v r2 = *(const uint4v*)(h8 + (size_t)s2 * W + 16 * l);
        uint4v r3 = *(const uint4v*)(h8 + (size_t)s3 * W + 16 * l);
        float e0 = lrelu(a_src[s0 * H + hd] + adst);
        float e1 = lrelu(a_src[s1 * H + hd] + adst);
        float e2 = lrelu(a_src[s2 * H + hd] + adst);
        float e3 = lrelu(a_src[s3 * H + hd] + adst);
        float nm = fmaxf(fmaxf(fmaxf(e0, e1), fmaxf(e2, e3)), m);
        float scale = __expf(m - nm);
        m = nm;
        float w0 = __expf(e0 - m), w1 = __expf(e1 - m);
        float w2 = __expf(e2 - m), w3 = __expf(e3 - m);
        ssum = ssum * scale + ((w0 + w1) + (w2 + w3));
        #pragma unroll
        for (int d = 0; d < 4; ++d) {
            f32x2 l0 = __builtin_amdgcn_cvt_pk_f32_fp8(r0[d], false);
            f32x2 h0 = __builtin_amdgcn_cvt_pk_f32_fp8(r0[d], true);
            f32x2 l1 = __builtin_amdgcn_cvt_pk_f32_fp8(r1[d], false);
            f32x2 h1 = __builtin_amdgcn_cvt_pk_f32_fp8(r1[d], true);
            f32x2 l2 = __builtin_amdgcn_cvt_pk_f32_fp8(r2[d], false);
            f32x2 h2 = __builtin_amdgcn_cvt_pk_f32_fp8(r2[d], true);
            f32x2 l3 = __builtin_amdgcn_cvt_pk_f32_fp8(r3[d], false);
            f32x2 h3 = __builtin_amdgcn_cvt_pk_f32_fp8(r3[d], true);
            acc[d*4+0] = acc[d*4+0]*scale + w0*l0.x + w1*l1.x + w2*l2.x + w3*l3.x;
            acc[d*4+1] = acc[d*4+1]*scale + w0*l0.y + w1*l1.y + w2*l2.y + w3*l3.y;
            acc[d*4+2] = acc[d*4+2]*scale + w0*h0.x + w1*h1.x + w2*h2.x + w3*h3.x;
            acc[d*4+3] = acc[d*4+3]*scale + w0*h0.y + w1*h1.y + w2*h2.y + w3*h3.y;
        }
    }
    for (; i < re; ++i) {
        int s = csr_src[i];
        uint4v r = *(const uint4v*)(h8 + (size_t)s * W + 16 * l);
        float e = lrelu(a_src[s * H + hd] + adst);
        float nm = fmaxf(m, e);
        float scale = __expf(m - nm);
        m = nm;
        float wgt = __expf(e - nm);
        ssum = ssum * scale + wgt;
        #pragma unroll
        for (int d = 0; d < 4; ++d) {
            f32x2 lo = __builtin_amdgcn_cvt_pk_f32_fp8(r[d], false);
            f32x2 hi = __builtin_amdgcn_cvt_pk_f32_fp8(r[d], true);
            acc[d*4+0] = acc[d*4+0]*scale + wgt*lo.x;
            acc[d*4+1] = acc[d*4+1]*scale + wgt*lo.y;
            acc[d*4+2] = acc[d*4+2]*scale + wgt*hi.x;
            acc[d*4+3] = acc[d*4+3]*scale + wgt*hi.y;
        }
    }

    float inv = 1.f / (ssum + 1e-16f);
    if (act) {
        short8 o0, o1;
        #pragma unroll
        for (int j = 0; j < 8; ++j) {
            float v = acc[j] * inv + bias[16 * l + j];
            o0[j] = (short)f2b(v > 0.f ? v : 0.f);
            float v2 = acc[8 + j] * inv + bias[16 * l + 8 + j];
            o1[j] = (short)f2b(v2 > 0.f ? v2 : 0.f);
        }
        *(short8*)(out + (size_t)n * W + 16 * l) = o0;
        *(short8*)(out + (size_t)n * W + 16 * l + 8) = o1;
    }
}

// ---------------------------------------------------------------------------
// Layer-3 aggregate (H=1, C=32, bf16): one wave/node, 16 edge groups x 4 lanes.
// ---------------------------------------------------------------------------
__global__ void gat_agg_c32(const ushort* __restrict__ h, const float* __restrict__ a_src,
                            const float* __restrict__ a_dst, const int* __restrict__ row_start,
                            const int* __restrict__ csr_src, const float* __restrict__ bias,
                            ushort* __restrict__ out, int N) {
    int n = (blockIdx.x * blockDim.x + threadIdx.x) >> 6;
    int lane = threadIdx.x & 63;
    if (n >= N) return;
    int g = lane >> 2;      // edge group 0..15
    int q = lane & 3;       // row chunk: channels [8q, 8q+8)
    float adst = a_dst[n];
    int rs = row_start[n];
    int total = row_start[n + 1] - rs + 1;   // + self loop (k==0)

    float m = -1e30f, ssum = 0.f;
    float acc[8];
    #pragma unroll
    for (int j = 0; j < 8; ++j) acc[j] = 0.f;

    for (int k = g; k < total; k += 16) {
        int s = (k == 0) ? n : csr_src[rs + k - 1];
        float e = lrelu(a_src[s] + adst);
        float nm = fmaxf(m, e);
        float scale = __expf(m - nm);        // m=-1e30 -> 0
        m = nm;
        float w = __expf(e - nm);
        ssum = ssum * scale + w;
        short8 r = *(const short8*)(h + (size_t)s * 32 + 8 * q);
        #pragma unroll
        for (int j = 0; j < 8; ++j) acc[j] = acc[j] * scale + w * b2f((ushort)r[j]);
    }

    #pragma unroll
    for (int off = 4; off < 64; off <<= 1) {
        float m2 = __shfl_xor(m, off);
        float s2 = __shfl_xor(ssum, off);
        float nm = fmaxf(m, m2);
        float sc1 = __expf(m - nm), sc2 = __expf(m2 - nm);
        ssum = ssum * sc1 + s2 * sc2;
        #pragma unroll
        for (int j = 0; j < 8; ++j) {
            float a2 = __shfl_xor(acc[j], off);
            acc[j] = acc[j] * sc1 + a2 * sc2;
        }
        m = nm;
    }

    if (lane < 4) {
        float inv = 1.f / (ssum + 1e-16f);
        short8 o;
        #pragma unroll
        for (int j = 0; j < 8; ++j) {
            float v = acc[j] * inv + bias[8 * lane + j];
            o[j] = (short)f2b(v > 0.f ? v : 0.f);
        }
        *(short8*)(out + (size_t)n * 32 + 8 * lane) = o;
    }
}

// ---------------------------------------------------------------------------
// global_add_pool: 2 nodes per wave (32 lanes each over 32 channels)
// ---------------------------------------------------------------------------
__global__ void pool_kernel(const ushort* __restrict__ x, const int* __restrict__ batch,
                            float* __restrict__ g, int N) {
    int wid = (blockIdx.x * blockDim.x + threadIdx.x) >> 6;
    int lane = threadIdx.x & 63;
    int node = wid * 2 + (lane >> 5);
    if (node >= N) return;
    int c = lane & 31;
    int b = batch[node];
    atomicAdd(&g[b * 32 + c], b2f(x[(size_t)node * 32 + c]));
}

__global__ void mlp1_kernel(const float* __restrict__ g, const float* __restrict__ w,
                            const float* __restrict__ b, float* __restrict__ hid) {
    int idx = blockIdx.x * blockDim.x + threadIdx.x;
    if (idx >= NG * 1024) return;
    int gr = idx >> 10, o = idx & 1023;
    float s = b[o];
    const float* gp = g + gr * 32;
    const float* wp = w + o * 32;
    #pragma unroll
    for (int k = 0; k < 32; ++k) s += gp[k] * wp[k];
    hid[idx] = s > 0.f ? s : 0.f;
}

__global__ void mlp2_kernel(const float* __restrict__ hid, const float* __restrict__ w2,
                            const float* __restrict__ b2, float* __restrict__ outp) {
    int wid = (blockIdx.x * blockDim.x + threadIdx.x) >> 6;
    int lane = threadIdx.x & 63;
    if (wid >= NG) return;
    float s = 0.f;
    for (int k = lane; k < 1024; k += 64) s += hid[wid * 1024 + k] * w2[k];
    for (int off = 32; off; off >>= 1) s += __shfl_down(s, off);
    if (lane == 0) outp[wid] = 1.f / (1.f + expf(-(s + b2[0])));
}

// ---------------------------------------------------------------------------
static inline size_t al256(size_t x) { return (x + 255) & ~(size_t)255; }

extern "C" void kernel_launch(void* const* d_in, const int* in_sizes, int n_in,
                              void* d_out, int out_size, void* d_ws, size_t ws_size,
                              hipStream_t stream) {
    const float* x      = (const float*)d_in[0];
    const float* W1     = (const float*)d_in[1];
    const float* as1    = (const float*)d_in[2];
    const float* ad1    = (const float*)d_in[3];
    const float* b1     = (const float*)d_in[4];
    const float* W2     = (const float*)d_in[5];
    const float* as2    = (const float*)d_in[6];
    const float* ad2    = (const float*)d_in[7];
    const float* b2     = (const float*)d_in[8];
    const float* W3     = (const float*)d_in[9];
    const float* as3    = (const float*)d_in[10];
    const float* ad3    = (const float*)d_in[11];
    const float* b3     = (const float*)d_in[12];
    const float* lin_w  = (const float*)d_in[13];
    const float* lin_b  = (const float*)d_in[14];
    const float* lin2_w = (const float*)d_in[15];
    const float* lin2_b = (const float*)d_in[16];
    const int*   ei     = (const int*)d_in[17];
    const int*   batch  = (const int*)d_in[18];
    float* outp = (float*)d_out;

    const int E = in_sizes[17] / 2;
    const int* e_src = ei;
    const int* e_dst = ei + E;

    // workspace carve-up
    char* p = (char*)d_ws;
    ushort* h_bf   = (ushort*)p; p += al256((size_t)NN * 480 * 2);
    ushort* o_bf   = (ushort*)p; p += al256((size_t)NN * 480 * 2);
    unsigned char* h_f8 = (unsigned char*)p; p += al256((size_t)NN * 480);
    ushort* x_bf   = (ushort*)p; p += al256((size_t)NN * 64 * 2);
    ushort* w1_bf  = (ushort*)p; p += al256((size_t)320 * 64 * 2);
    ushort* w2_bf  = (ushort*)p; p += al256((size_t)480 * 320 * 2);
    ushort* w3_bf  = (ushort*)p; p += al256((size_t)32 * 480 * 2);
    float* asrc    = (float*)p; p += al256((size_t)NN * 5 * 4);
    float* adst    = (float*)p; p += al256((size_t)NN * 5 * 4);
    int*   row_st  = (int*)p;   p += al256((size_t)(NN + 1) * 4);
    int*   cnt     = (int*)p;   p += al256((size_t)NN * 4);   // reused as cursor
    int*   csr_src = (int*)p;   p += al256((size_t)NE * 4);
    float* gpool   = (float*)p; p += al256((size_t)NG * 32 * 4);
    float* hidden  = (float*)p; p += al256((size_t)NG * 1024 * 4);
    (void)ws_size; (void)n_in; (void)out_size;

    dim3 blk(256);

    // ---- CSR build ----
    hipMemsetAsync(cnt, 0, NN * 4, stream);
    count_kernel<<<(E + 255) / 256, 256, 0, stream>>>(e_dst, cnt, E);
    scan_kernel<<<1, 1024, 0, stream>>>(cnt, row_st, NN);
    hipMemsetAsync(cnt, 0, NN * 4, stream);
    fill_kernel<<<(E + 255) / 256, 256, 0, stream>>>(e_src, e_dst, row_st, cnt, csr_src, E);

    // ---- converts (single launch) ----
    {
        int tot = CVT_N0 + CVT_N1 + CVT_N2 + CVT_N3;
        f2b4_kernel<<<(tot + 255) / 256, blk, 0, stream>>>(x, x_bf, W1, w1_bf, W2, w2_bf, W3, w3_bf);
    }

    const int MPAN = (NN + 63) / 64;     // 313 row panels
    const int NBLK = (NN + 3) / 4;       // aggregates: one wave per node
    // ---- layer 1: K=64 -> H=5, C=64 (width 320); BN=64=C, gx=5=H ----
    {
        gemm_lds<64, 4, 5><<<5 * MPAN, blk, 0, stream>>>(x_bf, w1_bf, h_bf, as1, ad1, asrc, adst, NN, 320, 5);
        b2f8_kernel<<<(NN * 320 / 8 + 255) / 256, blk, 0, stream>>>(h_bf, h_f8, NN * 320 / 8);
        gat_agg_f8<5, 64><<<NBLK, blk, 0, stream>>>(h_f8, asrc, adst, row_st, csr_src, b1, o_bf, NN);
    }
    // ---- layer 2: K=320 -> H=5, C=96 (width 480); BN=96=C, gx=5=H ----
    {
        gemm_lds<320, 6, 5><<<5 * MPAN, blk, 0, stream>>>(o_bf, w2_bf, h_bf, as2, ad2, asrc, adst, NN, 480, 5);
        b2f8_kernel<<<(NN * 480 / 8 + 255) / 256, blk, 0, stream>>>(h_bf, h_f8, NN * 480 / 8);
        gat_agg_f8<5, 96><<<NBLK, blk, 0, stream>>>(h_f8, asrc, adst, row_st, csr_src, b2, o_bf, NN);
    }
    // ---- layer 3: K=480 -> H=1, C=32 (width 32); BN=32=C, gx=1=H ----
    {
        gemm_lds<480, 2, 1><<<1 * MPAN, blk, 0, stream>>>(o_bf, w3_bf, h_bf, as3, ad3, asrc, adst, NN, 32, 1);
        gat_agg_c32<<<NBLK, blk, 0, stream>>>(h_bf, asrc, adst, row_st, csr_src, b3, o_bf, NN);
    }
    // ---- pool + MLP ----
    hipMemsetAsync(gpool, 0, NG * 32 * 4, stream);
    pool_kernel<<<(NN / 2 * 64 + 255) / 256, blk, 0, stream>>>(o_bf, batch, gpool, NN);
    mlp1_kernel<<<(NG * 1024 + 255) / 256, blk, 0, stream>>>(gpool, lin_w, lin_b, hidden);
    mlp2_kernel<<<(NG * 64 + 255) / 256, blk, 0, stream>>>(hidden, lin2_w, lin2_b, outp);
}

// Round 9
// 212.108 us; speedup vs baseline: 4.7675x; 1.1979x over previous
//
#include <hip/hip_runtime.h>
#include <math.h>

#define NN 20000
#define NE 320000
#define NG 128

typedef short short8 __attribute__((ext_vector_type(8)));
typedef float f32x4 __attribute__((ext_vector_type(4)));
typedef float f32x2 __attribute__((ext_vector_type(2)));
typedef unsigned short ushort;
typedef unsigned short ushort4v __attribute__((ext_vector_type(4)));
typedef float float4v __attribute__((ext_vector_type(4)));
typedef unsigned int uint;
typedef unsigned int uint2v __attribute__((ext_vector_type(2)));

__device__ __forceinline__ float b2f(ushort u) {
    unsigned int v = ((unsigned int)u) << 16;
    return __uint_as_float(v);
}
__device__ __forceinline__ ushort f2b(float f) {
    unsigned int u = __float_as_uint(f);
    u = (u + 0x7fff + ((u >> 16) & 1)) >> 16;   // RNE
    return (ushort)u;
}
__device__ __forceinline__ float lrelu(float x) { return x >= 0.f ? x : 0.2f * x; }
__device__ __forceinline__ unsigned char f2f8(float v) {
    return (unsigned char)(__builtin_amdgcn_cvt_pk_fp8_f32(v, v, 0, false) & 0xff);
}
// decode 8 fp8 bytes (uint2v) -> 4 packed f32x2 (literal word selects)
__device__ __forceinline__ void dec8(uint2v r, f32x2 d[4]) {
    d[0] = __builtin_amdgcn_cvt_pk_f32_fp8(r.x, false);
    d[1] = __builtin_amdgcn_cvt_pk_f32_fp8(r.x, true);
    d[2] = __builtin_amdgcn_cvt_pk_f32_fp8(r.y, false);
    d[3] = __builtin_amdgcn_cvt_pk_f32_fp8(r.y, true);
}

// ---------------------------------------------------------------------------
// fused f32 -> bf16 convert of x, W1, W2, W3 (one launch, float4 vectorized)
// ---------------------------------------------------------------------------
#define CVT_N0 (NN * 64 / 4)
#define CVT_N1 (320 * 64 / 4)
#define CVT_N2 (480 * 320 / 4)
#define CVT_N3 (32 * 480 / 4)
__global__ void f2b4_kernel(const float* __restrict__ a0, ushort* __restrict__ o0,
                            const float* __restrict__ a1, ushort* __restrict__ o1,
                            const float* __restrict__ a2, ushort* __restrict__ o2,
                            const float* __restrict__ a3, ushort* __restrict__ o3) {
    int i = blockIdx.x * blockDim.x + threadIdx.x;
    const float* src; ushort* dst; int li;
    if (i < CVT_N0) { src = a0; dst = o0; li = i; }
    else if (i < CVT_N0 + CVT_N1) { src = a1; dst = o1; li = i - CVT_N0; }
    else if (i < CVT_N0 + CVT_N1 + CVT_N2) { src = a2; dst = o2; li = i - CVT_N0 - CVT_N1; }
    else if (i < CVT_N0 + CVT_N1 + CVT_N2 + CVT_N3) { src = a3; dst = o3; li = i - CVT_N0 - CVT_N1 - CVT_N2; }
    else return;
    float4v v = *(const float4v*)(src + (size_t)li * 4);
    ushort4v r;
    r.x = f2b(v.x); r.y = f2b(v.y); r.z = f2b(v.z); r.w = f2b(v.w);
    *(ushort4v*)(dst + (size_t)li * 4) = r;
}

// ---------------------------------------------------------------------------
// CSR build: count -> parallel scan -> fill
// ---------------------------------------------------------------------------
__global__ void count_kernel(const int* __restrict__ dst, int* __restrict__ cnt, int E) {
    int i = blockIdx.x * blockDim.x + threadIdx.x;
    if (i < E) atomicAdd(&cnt[dst[i]], 1);
}

__global__ __launch_bounds__(1024) void scan_kernel(const int* __restrict__ cnt,
                                                    int* __restrict__ row_start, int n) {
    __shared__ int sh[1024];
    int tid = threadIdx.x;
    int base = tid * 20;
    int local[20];
    int s = 0;
    #pragma unroll
    for (int k = 0; k < 20; ++k) {
        int idx = base + k;
        int v = (idx < n) ? cnt[idx] : 0;
        local[k] = s;           // exclusive within chunk
        s += v;
    }
    sh[tid] = s;
    __syncthreads();
    for (int off = 1; off < 1024; off <<= 1) {
        int t = (tid >= off) ? sh[tid - off] : 0;
        __syncthreads();
        sh[tid] += t;
        __syncthreads();
    }
    int pre = (tid == 0) ? 0 : sh[tid - 1];
    #pragma unroll
    for (int k = 0; k < 20; ++k) {
        int idx = base + k;
        if (idx < n) row_start[idx] = pre + local[k];
    }
    if (tid == 1023) row_start[n] = sh[1023];
}

__global__ void fill_kernel(const int* __restrict__ src, const int* __restrict__ dst,
                            const int* __restrict__ row_start, int* __restrict__ cursor,
                            int* __restrict__ csr_src, int E) {
    int i = blockIdx.x * blockDim.x + threadIdx.x;
    if (i < E) {
        int d = dst[i];
        int pos = atomicAdd(&cursor[d], 1);
        csr_src[row_start[d] + pos] = src[i];
    }
}

// ---------------------------------------------------------------------------
// MFMA GEMM with LDS-staged B panel + reg double-buffering + FUSED per-head
// attention dots in the epilogue (BN == C, gridx == H; head = bx).
// F8 variant stores C as fp8 e4m3 bytes (direct from f32 acc) instead of bf16.
// ---------------------------------------------------------------------------
template <int K, int NF, int H, bool F8>
__global__ __launch_bounds__(256) void gemm_lds(const ushort* __restrict__ A,
                                                const ushort* __restrict__ B,
                                                ushort* __restrict__ C,
                                                unsigned char* __restrict__ C8,
                                                const float* __restrict__ att_src,
                                                const float* __restrict__ att_dst,
                                                float* __restrict__ a_src,
                                                float* __restrict__ a_dst,
                                                int M, int N, int gridx) {
    constexpr int BN = NF * 16;
    constexpr int KP = K + 8;            // padded row (bf16 elems)
    constexpr int KS = K / 32;           // k-steps
    __shared__ ushort Bs[BN][KP];

    const int nwg = gridDim.x;
    int bid = blockIdx.x;
    {   // bijective XCD chunk swizzle (m204)
        int q = nwg >> 3, r = nwg & 7;
        int xcd = bid & 7, idx = bid >> 3;
        bid = (xcd < r ? xcd * (q + 1) : r * (q + 1) + (xcd - r) * q) + idx;
    }
    const int by = bid / gridx;          // row panel (64 rows)
    const int bx = bid % gridx;          // col tile == head index
    const int bn = bx * BN;

    const int tid = threadIdx.x;
    const int w = tid >> 6;
    const int lane = tid & 63;
    const int l15 = lane & 15;
    const int lhi = lane >> 4;           // 0..3

    // ---- stage B panel (BN x K) into LDS, short8 chunks ----
    constexpr int NCH = BN * (K / 8);
    for (int i = tid; i < NCH; i += 256) {
        int r = i / (K / 8), c8 = i % (K / 8);
        short8 v = *(const short8*)(B + (size_t)(bn + r) * K + c8 * 8);
        *(short8*)(&Bs[r][c8 * 8]) = v;
    }
    __syncthreads();

    const int bm = by * 64 + w * 16;
    int arow = bm + l15;
    if (arow >= M) arow = M - 1;         // clamp; stores masked
    const ushort* ap = A + (size_t)arow * K + lhi * 8;

    f32x4 acc[NF];
    #pragma unroll
    for (int f = 0; f < NF; ++f) acc[f] = (f32x4){0.f, 0.f, 0.f, 0.f};

    short8 a_cur = *(const short8*)ap;
    short8 b_cur[NF], b_nxt[NF];
    #pragma unroll
    for (int f = 0; f < NF; ++f)
        b_cur[f] = *(const short8*)(&Bs[f * 16 + l15][lhi * 8]);

    #pragma unroll
    for (int ks = 0; ks < KS; ++ks) {
        short8 a_nxt = a_cur;
        if (ks + 1 < KS) {
            a_nxt = *(const short8*)(ap + (ks + 1) * 32);
            #pragma unroll
            for (int f = 0; f < NF; ++f)
                b_nxt[f] = *(const short8*)(&Bs[f * 16 + l15][(ks + 1) * 32 + lhi * 8]);
        }
        #pragma unroll
        for (int f = 0; f < NF; ++f)
            acc[f] = __builtin_amdgcn_mfma_f32_16x16x32_bf16(a_cur, b_cur[f], acc[f], 0, 0, 0);
        a_cur = a_nxt;
        #pragma unroll
        for (int f = 0; f < NF; ++f) b_cur[f] = b_nxt[f];
    }

    // ---- C store ----
    #pragma unroll
    for (int f = 0; f < NF; ++f) {
        #pragma unroll
        for (int j = 0; j < 4; ++j) {
            int row = bm + lhi * 4 + j;
            if (row < M) {
                if (F8) C8[(size_t)row * N + bn + f * 16 + l15] = f2f8(acc[f][j]);
                else    C[(size_t)row * N + bn + f * 16 + l15] = f2b(acc[f][j]);
            }
        }
    }

    // ---- fused attention dots (BN == C, head = bx) ----
    float as_v[NF], ad_v[NF];
    #pragma unroll
    for (int f = 0; f < NF; ++f) {
        as_v[f] = att_src[bx * BN + f * 16 + l15];
        ad_v[f] = att_dst[bx * BN + f * 16 + l15];
    }
    #pragma unroll
    for (int j = 0; j < 4; ++j) {
        float ps = 0.f, pd = 0.f;
        #pragma unroll
        for (int f = 0; f < NF; ++f) {
            ps += acc[f][j] * as_v[f];
            pd += acc[f][j] * ad_v[f];
        }
        #pragma unroll
        for (int off = 1; off < 16; off <<= 1) {
            ps += __shfl_xor(ps, off);
            pd += __shfl_xor(pd, off);
        }
        int row = bm + lhi * 4 + j;
        if (l15 == 0 && row < M) {
            a_src[row * H + bx] = ps;
            a_dst[row * H + bx] = pd;
        }
    }
}

// ---------------------------------------------------------------------------
// fp8 GAT aggregate: ONE WAVE PER NODE, all heads, online softmax.
// Lane l handles 8 fp8 channels [8l, 8l+8) via one 8B load (W/8 active lanes:
// 40 for W=320, 60 for W=480). f32x2 packed accumulators -> v_pk_fma_f32.
// ---------------------------------------------------------------------------
template <int H, int C>
__global__ void gat_agg_f8(const unsigned char* __restrict__ h8,
                           const float* __restrict__ a_src, const float* __restrict__ a_dst,
                           const int* __restrict__ row_start, const int* __restrict__ csr_src,
                           const float* __restrict__ bias, ushort* __restrict__ out, int N) {
    constexpr int W = H * C;         // channels == bytes per row
    constexpr int VL = W / 8;        // active lanes (40 or 60)
    int n = (blockIdx.x * blockDim.x + threadIdx.x) >> 6;
    int lane = threadIdx.x & 63;
    if (n >= N) return;
    bool act = lane < VL;
    int l = act ? lane : 0;
    int hd = (8 * l) / C;
    float adst = a_dst[n * H + hd];

    // self loop initializes online state (weight exp(0)=1)
    float m = lrelu(a_src[n * H + hd] + adst);
    float ssum = 1.f;
    f32x2 acc2[4];
    {
        uint2v r = *(const uint2v*)(h8 + (size_t)n * W + 8 * l);
        dec8(r, acc2);
    }

    int rs = row_start[n], re = row_start[n + 1];
    int i = rs;
    for (; i + 4 <= re; i += 4) {
        int s0 = csr_src[i], s1 = csr_src[i + 1], s2 = csr_src[i + 2], s3 = csr_src[i + 3];
        uint2v r0 = *(const uint2v*)(h8 + (size_t)s0 * W + 8 * l);
        uint2v r1 = *(const uint2v*)(h8 + (size_t)s1 * W + 8 * l);
        uint2v r2 = *(const uint2v*)(h8 + (size_t)s2 * W + 8 * l);
        uint2v r3 = *(const uint2v*)(h8 + (size_t)s3 * W + 8 * l);
        float e0 = lrelu(a_src[s0 * H + hd] + adst);
        float e1 = lrelu(a_src[s1 * H + hd] + adst);
        float e2 = lrelu(a_src[s2 * H + hd] + adst);
        float e3 = lrelu(a_src[s3 * H + hd] + adst);
        float nm = fmaxf(fmaxf(fmaxf(e0, e1), fmaxf(e2, e3)), m);
        float scale = __expf(m - nm);
        m = nm;
        float w0 = __expf(e0 - m), w1 = __expf(e1 - m);
        float w2 = __expf(e2 - m), w3 = __expf(e3 - m);
        ssum = ssum * scale + ((w0 + w1) + (w2 + w3));
        f32x2 d0[4], d1[4], d2[4], d3[4];
        dec8(r0, d0); dec8(r1, d1); dec8(r2, d2); dec8(r3, d3);
        f32x2 sc = {scale, scale};
        f32x2 vw0 = {w0, w0}, vw1 = {w1, w1}, vw2 = {w2, w2}, vw3 = {w3, w3};
        #pragma unroll
        for (int d = 0; d < 4; ++d) {
            f32x2 t = acc2[d] * sc;
            t += vw0 * d0[d];
            t += vw1 * d1[d];
            t += vw2 * d2[d];
            t += vw3 * d3[d];
            acc2[d] = t;
        }
    }
    for (; i < re; ++i) {
        int s = csr_src[i];
        uint2v r = *(const uint2v*)(h8 + (size_t)s * W + 8 * l);
        float e = lrelu(a_src[s * H + hd] + adst);
        float nm = fmaxf(m, e);
        float scale = __expf(m - nm);
        m = nm;
        float wgt = __expf(e - nm);
        ssum = ssum * scale + wgt;
        f32x2 dd[4];
        dec8(r, dd);
        f32x2 sc = {scale, scale};
        f32x2 vw = {wgt, wgt};
        #pragma unroll
        for (int d = 0; d < 4; ++d) acc2[d] = acc2[d] * sc + vw * dd[d];
    }

    float inv = 1.f / (ssum + 1e-16f);
    if (act) {
        short8 o;
        #pragma unroll
        for (int d = 0; d < 4; ++d) {
            #pragma unroll
            for (int e = 0; e < 2; ++e) {
                float v = acc2[d][e] * inv + bias[8 * l + 2 * d + e];
                o[2 * d + e] = (short)f2b(v > 0.f ? v : 0.f);
            }
        }
        *(short8*)(out + (size_t)n * W + 8 * l) = o;
    }
}

// ---------------------------------------------------------------------------
// Layer-3 aggregate (H=1, C=32, bf16): one wave/node, 16 edge groups x 4 lanes.
// ---------------------------------------------------------------------------
__global__ void gat_agg_c32(const ushort* __restrict__ h, const float* __restrict__ a_src,
                            const float* __restrict__ a_dst, const int* __restrict__ row_start,
                            const int* __restrict__ csr_src, const float* __restrict__ bias,
                            ushort* __restrict__ out, int N) {
    int n = (blockIdx.x * blockDim.x + threadIdx.x) >> 6;
    int lane = threadIdx.x & 63;
    if (n >= N) return;
    int g = lane >> 2;      // edge group 0..15
    int q = lane & 3;       // row chunk: channels [8q, 8q+8)
    float adst = a_dst[n];
    int rs = row_start[n];
    int total = row_start[n + 1] - rs + 1;   // + self loop (k==0)

    float m = -1e30f, ssum = 0.f;
    float acc[8];
    #pragma unroll
    for (int j = 0; j < 8; ++j) acc[j] = 0.f;

    for (int k = g; k < total; k += 16) {
        int s = (k == 0) ? n : csr_src[rs + k - 1];
        float e = lrelu(a_src[s] + adst);
        float nm = fmaxf(m, e);
        float scale = __expf(m - nm);        // m=-1e30 -> 0
        m = nm;
        float w = __expf(e - nm);
        ssum = ssum * scale + w;
        short8 r = *(const short8*)(h + (size_t)s * 32 + 8 * q);
        #pragma unroll
        for (int j = 0; j < 8; ++j) acc[j] = acc[j] * scale + w * b2f((ushort)r[j]);
    }

    #pragma unroll
    for (int off = 4; off < 64; off <<= 1) {
        float m2 = __shfl_xor(m, off);
        float s2 = __shfl_xor(ssum, off);
        float nm = fmaxf(m, m2);
        float sc1 = __expf(m - nm), sc2 = __expf(m2 - nm);
        ssum = ssum * sc1 + s2 * sc2;
        #pragma unroll
        for (int j = 0; j < 8; ++j) {
            float a2 = __shfl_xor(acc[j], off);
            acc[j] = acc[j] * sc1 + a2 * sc2;
        }
        m = nm;
    }

    if (lane < 4) {
        float inv = 1.f / (ssum + 1e-16f);
        short8 o;
        #pragma unroll
        for (int j = 0; j < 8; ++j) {
            float v = acc[j] * inv + bias[8 * lane + j];
            o[j] = (short)f2b(v > 0.f ? v : 0.f);
        }
        *(short8*)(out + (size_t)n * 32 + 8 * lane) = o;
    }
}

// ---------------------------------------------------------------------------
// global_add_pool: 2 nodes per wave (32 lanes each over 32 channels)
// ---------------------------------------------------------------------------
__global__ void pool_kernel(const ushort* __restrict__ x, const int* __restrict__ batch,
                            float* __restrict__ g, int N) {
    int wid = (blockIdx.x * blockDim.x + threadIdx.x) >> 6;
    int lane = threadIdx.x & 63;
    int node = wid * 2 + (lane >> 5);
    if (node >= N) return;
    int c = lane & 31;
    int b = batch[node];
    atomicAdd(&g[b * 32 + c], b2f(x[(size_t)node * 32 + c]));
}

__global__ void mlp1_kernel(const float* __restrict__ g, const float* __restrict__ w,
                            const float* __restrict__ b, float* __restrict__ hid) {
    int idx = blockIdx.x * blockDim.x + threadIdx.x;
    if (idx >= NG * 1024) return;
    int gr = idx >> 10, o = idx & 1023;
    float s = b[o];
    const float* gp = g + gr * 32;
    const float* wp = w + o * 32;
    #pragma unroll
    for (int k = 0; k < 32; ++k) s += gp[k] * wp[k];
    hid[idx] = s > 0.f ? s : 0.f;
}

__global__ void mlp2_kernel(const float* __restrict__ hid, const float* __restrict__ w2,
                            const float* __restrict__ b2, float* __restrict__ outp) {
    int wid = (blockIdx.x * blockDim.x + threadIdx.x) >> 6;
    int lane = threadIdx.x & 63;
    if (wid >= NG) return;
    float s = 0.f;
    for (int k = lane; k < 1024; k += 64) s += hid[wid * 1024 + k] * w2[k];
    for (int off = 32; off; off >>= 1) s += __shfl_down(s, off);
    if (lane == 0) outp[wid] = 1.f / (1.f + expf(-(s + b2[0])));
}

// ---------------------------------------------------------------------------
static inline size_t al256(size_t x) { return (x + 255) & ~(size_t)255; }

extern "C" void kernel_launch(void* const* d_in, const int* in_sizes, int n_in,
                              void* d_out, int out_size, void* d_ws, size_t ws_size,
                              hipStream_t stream) {
    const float* x      = (const float*)d_in[0];
    const float* W1     = (const float*)d_in[1];
    const float* as1    = (const float*)d_in[2];
    const float* ad1    = (const float*)d_in[3];
    const float* b1     = (const float*)d_in[4];
    const float* W2     = (const float*)d_in[5];
    const float* as2    = (const float*)d_in[6];
    const float* ad2    = (const float*)d_in[7];
    const float* b2     = (const float*)d_in[8];
    const float* W3     = (const float*)d_in[9];
    const float* as3    = (const float*)d_in[10];
    const float* ad3    = (const float*)d_in[11];
    const float* b3     = (const float*)d_in[12];
    const float* lin_w  = (const float*)d_in[13];
    const float* lin_b  = (const float*)d_in[14];
    const float* lin2_w = (const float*)d_in[15];
    const float* lin2_b = (const float*)d_in[16];
    const int*   ei     = (const int*)d_in[17];
    const int*   batch  = (const int*)d_in[18];
    float* outp = (float*)d_out;

    const int E = in_sizes[17] / 2;
    const int* e_src = ei;
    const int* e_dst = ei + E;

    // workspace carve-up
    char* p = (char*)d_ws;
    ushort* h_bf   = (ushort*)p; p += al256((size_t)NN * 480 * 2);
    ushort* o_bf   = (ushort*)p; p += al256((size_t)NN * 480 * 2);
    unsigned char* h_f8 = (unsigned char*)p; p += al256((size_t)NN * 480);
    ushort* x_bf   = (ushort*)p; p += al256((size_t)NN * 64 * 2);
    ushort* w1_bf  = (ushort*)p; p += al256((size_t)320 * 64 * 2);
    ushort* w2_bf  = (ushort*)p; p += al256((size_t)480 * 320 * 2);
    ushort* w3_bf  = (ushort*)p; p += al256((size_t)32 * 480 * 2);
    float* asrc    = (float*)p; p += al256((size_t)NN * 5 * 4);
    float* adst    = (float*)p; p += al256((size_t)NN * 5 * 4);
    int*   row_st  = (int*)p;   p += al256((size_t)(NN + 1) * 4);
    int*   cnt     = (int*)p;   p += al256((size_t)NN * 4);   // reused as cursor
    int*   csr_src = (int*)p;   p += al256((size_t)NE * 4);
    float* gpool   = (float*)p; p += al256((size_t)NG * 32 * 4);
    float* hidden  = (float*)p; p += al256((size_t)NG * 1024 * 4);
    (void)ws_size; (void)n_in; (void)out_size;

    dim3 blk(256);

    // ---- CSR build ----
    hipMemsetAsync(cnt, 0, NN * 4, stream);
    count_kernel<<<(E + 255) / 256, 256, 0, stream>>>(e_dst, cnt, E);
    scan_kernel<<<1, 1024, 0, stream>>>(cnt, row_st, NN);
    hipMemsetAsync(cnt, 0, NN * 4, stream);
    fill_kernel<<<(E + 255) / 256, 256, 0, stream>>>(e_src, e_dst, row_st, cnt, csr_src, E);

    // ---- converts (single launch) ----
    {
        int tot = CVT_N0 + CVT_N1 + CVT_N2 + CVT_N3;
        f2b4_kernel<<<(tot + 255) / 256, blk, 0, stream>>>(x, x_bf, W1, w1_bf, W2, w2_bf, W3, w3_bf);
    }

    const int MPAN = (NN + 63) / 64;     // 313 row panels
    const int NBLK = (NN + 3) / 4;       // aggregates: one wave per node
    // ---- layer 1: K=64 -> H=5, C=64 (width 320); fp8 h + fused dots ----
    {
        gemm_lds<64, 4, 5, true><<<5 * MPAN, blk, 0, stream>>>(x_bf, w1_bf, h_bf, h_f8, as1, ad1, asrc, adst, NN, 320, 5);
        gat_agg_f8<5, 64><<<NBLK, blk, 0, stream>>>(h_f8, asrc, adst, row_st, csr_src, b1, o_bf, NN);
    }
    // ---- layer 2: K=320 -> H=5, C=96 (width 480); fp8 h + fused dots ----
    {
        gemm_lds<320, 6, 5, true><<<5 * MPAN, blk, 0, stream>>>(o_bf, w2_bf, h_bf, h_f8, as2, ad2, asrc, adst, NN, 480, 5);
        gat_agg_f8<5, 96><<<NBLK, blk, 0, stream>>>(h_f8, asrc, adst, row_st, csr_src, b2, o_bf, NN);
    }
    // ---- layer 3: K=480 -> H=1, C=32 (width 32); bf16 h + fused dots ----
    {
        gemm_lds<480, 2, 1, false><<<1 * MPAN, blk, 0, stream>>>(o_bf, w3_bf, h_bf, h_f8, as3, ad3, asrc, adst, NN, 32, 1);
        gat_agg_c32<<<NBLK, blk, 0, stream>>>(h_bf, asrc, adst, row_st, csr_src, b3, o_bf, NN);
    }
    // ---- pool + MLP ----
    hipMemsetAsync(gpool, 0, NG * 32 * 4, stream);
    pool_kernel<<<(NN / 2 * 64 + 255) / 256, blk, 0, stream>>>(o_bf, batch, gpool, NN);
    mlp1_kernel<<<(NG * 1024 + 255) / 256, blk, 0, stream>>>(gpool, lin_w, lin_b, hidden);
    mlp2_kernel<<<(NG * 64 + 255) / 256, blk, 0, stream>>>(hidden, lin2_w, lin2_b, outp);
}